// Round 5
// baseline (636.076 us; speedup 1.0000x reference)
//
#include <hip/hip_runtime.h>

#define N_USERS 100000
#define N_ITEMS 50000
#define NEDGE   800000
#define NH      128
#define NTGT    8192
#define NNODE   250000      // 50K item slots (buys) + 100K user (rev) + 100K user (fol)
#define BASE_REV 50000
#define BASE_FOL 150000
#define NBUCK   588         // 196 buys (256 nodes) + 196 rev (512) + 196 fol (512)
#define NBLK    384         // binning blocks
#define NPB     6250        // edges per binning block: 384*6250 = 2400000 exactly
#define NRUN    (NBUCK * NBLK)        // 225792 per-(bucket,block) runs
#define NSCANB  441                   // 225792 / 512 exactly

// ---------------------------------------------------------------- bf16 helpers (RNE, manual — no hip_bf16 dep)
__device__ __forceinline__ unsigned rne_hi(float f) {
  unsigned u = __float_as_uint(f);
  u += 0x7FFFu + ((u >> 16) & 1u);
  return u & 0xFFFF0000u;
}
__device__ __forceinline__ unsigned pack2(float f0, float f1) {
  return (rne_hi(f0) >> 16) | rne_hi(f1);   // low ushort = f0, high = f1
}
__device__ __forceinline__ float blo(unsigned u) { return __uint_as_float(u << 16); }
__device__ __forceinline__ float bhi(unsigned u) { return __uint_as_float(u & 0xFFFF0000u); }

__device__ __forceinline__ int bucket_of(int n) {
  return (n < BASE_REV) ? (n >> 8)
       : (n < BASE_FOL) ? 196 + ((n - BASE_REV) >> 9)
                        : 392 + ((n - BASE_FOL) >> 9);
}

// ---------------------------------------------------------------- fp32 -> bf16 table conversion (8 elems/thread)
__global__ __launch_bounds__(256) void k_tobf16(const float* __restrict__ x,
                                                unsigned* __restrict__ y)
{
  int i = blockIdx.x * 256 + threadIdx.x;
  const float4* xp = (const float4*)x;
  float4 a = xp[(size_t)i * 2];
  float4 b = xp[(size_t)i * 2 + 1];
  ((uint4*)y)[i] = make_uint4(pack2(a.x, a.y), pack2(a.z, a.w),
                              pack2(b.x, b.y), pack2(b.z, b.w));
}

// ---------------------------------------------------------------- pass A: per-(bucket,block) histogram, LDS only
__global__ __launch_bounds__(256) void k_pcount(
    const int* __restrict__ db, const int* __restrict__ dr,
    const int* __restrict__ df, int* __restrict__ cntBB)
{
  __shared__ int h[NBUCK];
  int t = threadIdx.x, blk = blockIdx.x;
  for (int j = t; j < NBUCK; j += 256) h[j] = 0;
  __syncthreads();
  int ebase = blk * NPB;
  for (int i = t; i < NPB; i += 256) {
    int e = ebase + i, n;
    if (e < NEDGE)          n = db[e];
    else if (e < 2 * NEDGE) n = BASE_REV + dr[e - NEDGE];
    else                    n = BASE_FOL + df[e - 2 * NEDGE];
    atomicAdd(&h[bucket_of(n)], 1);
  }
  __syncthreads();
  for (int j = t; j < NBUCK; j += 256) cntBB[j * NBLK + blk] = h[j];
}

// ---------------------------------------------------------------- scan of 225792 counts (3 tiny kernels)
__global__ __launch_bounds__(256) void k_scanA(const int* __restrict__ cntBB,
                                               int* __restrict__ partial)
{
  int t = threadIdx.x;
  int base = blockIdx.x * 512;
  int s = cntBB[base + t] + cntBB[base + 256 + t];
  __shared__ int red[256];
  red[t] = s; __syncthreads();
  for (int d = 128; d > 0; d >>= 1) { if (t < d) red[t] += red[t + d]; __syncthreads(); }
  if (t == 0) partial[blockIdx.x] = red[0];
}

__global__ __launch_bounds__(256) void k_scanB(const int* __restrict__ partial,
                                               int* __restrict__ pbase)
{
  __shared__ int carry;
  __shared__ int wsum[4];
  int t = threadIdx.x, lane = t & 63, w = t >> 6;
  if (t == 0) carry = 0;
  __syncthreads();
  for (int base = 0; base < NSCANB; base += 256) {
    int orig = (base + t < NSCANB) ? partial[base + t] : 0;
    int v = orig;
    #pragma unroll
    for (int o = 1; o < 64; o <<= 1) { int u = __shfl_up(v, o); if (lane >= o) v += u; }
    if (lane == 63) wsum[w] = v;
    __syncthreads();
    int wb = 0;
    for (int i = 0; i < w; ++i) wb += wsum[i];
    int excl = carry + wb + v - orig;
    if (base + t < NSCANB) pbase[base + t] = excl;
    __syncthreads();
    if (t == 255) carry = excl + orig;
    __syncthreads();
  }
}

__global__ __launch_bounds__(256) void k_scanC(const int* __restrict__ cntBB,
                                               const int* __restrict__ pbase,
                                               int* __restrict__ sscan)
{
  int t = threadIdx.x, blk = blockIdx.x;
  int base = blk * 512;
  int a0 = cntBB[base + t * 2], a1 = cntBB[base + t * 2 + 1];
  int sum = a0 + a1;
  int lane = t & 63, w = t >> 6;
  int v = sum;
  #pragma unroll
  for (int o = 1; o < 64; o <<= 1) { int u = __shfl_up(v, o); if (lane >= o) v += u; }
  __shared__ int wsum[4];
  if (lane == 63) wsum[w] = v;
  __syncthreads();
  int wb = 0;
  for (int i = 0; i < w; ++i) wb += wsum[i];
  int excl = wb + v - sum;
  int P = pbase[blk];
  sscan[base + t * 2]     = P + excl;
  sscan[base + t * 2 + 1] = P + excl + a0;
  if (blk == NSCANB - 1 && t == 255)
    sscan[NRUN] = P + wsum[0] + wsum[1] + wsum[2] + wsum[3];   // == 3*NEDGE
}

// ---------------------------------------------------------------- pass B: scatter into pre-reserved runs (LDS cursors only)
// binned entry packs (local_node_in_bucket << 17) | src  (src < 2^17, local < 512)
__global__ __launch_bounds__(256) void k_pfill(
    const int* __restrict__ sb, const int* __restrict__ db,
    const int* __restrict__ sr, const int* __restrict__ dr,
    const int* __restrict__ sf, const int* __restrict__ df,
    const int* __restrict__ sscan, int* __restrict__ binned)
{
  __shared__ int cur[NBUCK];
  int t = threadIdx.x, blk = blockIdx.x;
  for (int j = t; j < NBUCK; j += 256) cur[j] = sscan[j * NBLK + blk];
  __syncthreads();
  int ebase = blk * NPB;
  for (int i = t; i < NPB; i += 256) {
    int e = ebase + i, n, s;
    if (e < NEDGE)          { n = db[e];                      s = sb[e]; }
    else if (e < 2 * NEDGE) { n = BASE_REV + dr[e - NEDGE];   s = sr[e - NEDGE]; }
    else                    { n = BASE_FOL + df[e - 2*NEDGE]; s = sf[e - 2*NEDGE]; }
    int b = bucket_of(n);
    int local = (n < BASE_REV) ? (n & 255)
              : (n < BASE_FOL) ? ((n - BASE_REV) & 511)
                               : ((n - BASE_FOL) & 511);
    int pos = atomicAdd(&cur[b], 1);
    binned[pos] = (local << 17) | s;
  }
}

// ---------------------------------------------------------------- pass C: per-bucket CSR build (1 block / bucket)
__global__ __launch_bounds__(256) void k_csr(
    const int* __restrict__ binned, const int* __restrict__ sscan,
    int* __restrict__ cnt, int* __restrict__ offs, int* __restrict__ esrc)
{
  int b = blockIdx.x;
  int n0, S;
  if (b < 196)      { n0 = b * 256;                    S = min(256, BASE_REV - n0); }
  else if (b < 392) { n0 = BASE_REV + (b - 196) * 512; S = min(512, BASE_FOL - n0); }
  else              { n0 = BASE_FOL + (b - 392) * 512; S = min(512, NNODE - n0); }
  int e0 = sscan[b * NBLK];
  int e1 = sscan[(b + 1) * NBLK];
  int t = threadIdx.x;
  __shared__ int h[512], fl[512];
  __shared__ int wsum[4];
  h[t] = 0; h[t + 256] = 0;
  __syncthreads();
  for (int e = e0 + t; e < e1; e += 256)
    atomicAdd(&h[binned[e] >> 17], 1);
  __syncthreads();
  int a0 = h[t * 2], a1 = h[t * 2 + 1];
  int v = a0 + a1;
  int lane = t & 63, w = t >> 6;
  #pragma unroll
  for (int o = 1; o < 64; o <<= 1) { int u = __shfl_up(v, o); if (lane >= o) v += u; }
  if (lane == 63) wsum[w] = v;
  __syncthreads();
  int wb = 0;
  for (int i = 0; i < w; ++i) wb += wsum[i];
  int excl = wb + v - (a0 + a1);
  fl[t * 2]     = e0 + excl;
  fl[t * 2 + 1] = e0 + excl + a0;
  if (t * 2 < S)     { cnt[n0 + t * 2]     = a0; offs[n0 + t * 2]     = e0 + excl + a0; }
  if (t * 2 + 1 < S) { cnt[n0 + t * 2 + 1] = a1; offs[n0 + t * 2 + 1] = e0 + excl + a0 + a1; }
  __syncthreads();
  for (int e = e0 + t; e < e1; e += 256) {
    int v2 = binned[e];
    int p = atomicAdd(&fl[v2 >> 17], 1);
    esrc[p] = v2 & 0x1FFFF;
  }
}

// ---------------------------------------------------------------- combine Wr1+Wr2, bl1+bl2
__global__ __launch_bounds__(256) void k_combine(
    const float* __restrict__ Wr, const float* __restrict__ bl,
    float* __restrict__ Wrc, float* __restrict__ bc)
{
  int i = blockIdx.x * 256 + threadIdx.x;
  if (i < 2 * NH * NH) {
    int l = i >> 14, r = i & (NH * NH - 1);
    Wrc[i] = Wr[(l * 3 + 1) * NH * NH + r] + Wr[(l * 3 + 2) * NH * NH + r];
  } else {
    int j = i - 2 * NH * NH;
    if (j < 2 * NH) {
      int l = j >> 7, r = j & (NH - 1);
      bc[j] = bl[(l * 3 + 1) * NH + r] + bl[(l * 3 + 2) * NH + r];
    }
  }
}

// ---------------------------------------------------------------- layer-1 mean aggregation (bf16 tables, bf16 out)
// Half-wave (32 lanes * 8B = 256B bf16 row) per node; fp32 accumulate.
__global__ __launch_bounds__(256) void k_agg1(
    const int* __restrict__ offs, const int* __restrict__ cnt,
    const int* __restrict__ esrc,
    const unsigned* __restrict__ ub, const unsigned* __restrict__ ib,
    unsigned* __restrict__ meanL1b)
{
  int n = blockIdx.x * 8 + (threadIdx.x >> 5);
  int sl = threadIdx.x & 31;
  if (n >= NNODE) return;
  const uint2* table = (n < BASE_REV) ? (const uint2*)ub
                     : (n < BASE_FOL) ? (const uint2*)ib
                                      : (const uint2*)ub;
  int end = offs[n], c = cnt[n], st = end - c;
  float ax = 0.f, ay = 0.f, az = 0.f, aw = 0.f;
  int k = st;
  for (; k + 7 < end; k += 8) {
    int s0 = esrc[k],     s1 = esrc[k + 1], s2 = esrc[k + 2], s3 = esrc[k + 3];
    int s4 = esrc[k + 4], s5 = esrc[k + 5], s6 = esrc[k + 6], s7 = esrc[k + 7];
    uint2 v0 = table[(size_t)s0 * 32 + sl];
    uint2 v1 = table[(size_t)s1 * 32 + sl];
    uint2 v2 = table[(size_t)s2 * 32 + sl];
    uint2 v3 = table[(size_t)s3 * 32 + sl];
    uint2 v4 = table[(size_t)s4 * 32 + sl];
    uint2 v5 = table[(size_t)s5 * 32 + sl];
    uint2 v6 = table[(size_t)s6 * 32 + sl];
    uint2 v7 = table[(size_t)s7 * 32 + sl];
    ax += ((blo(v0.x) + blo(v1.x)) + (blo(v2.x) + blo(v3.x))) + ((blo(v4.x) + blo(v5.x)) + (blo(v6.x) + blo(v7.x)));
    ay += ((bhi(v0.x) + bhi(v1.x)) + (bhi(v2.x) + bhi(v3.x))) + ((bhi(v4.x) + bhi(v5.x)) + (bhi(v6.x) + bhi(v7.x)));
    az += ((blo(v0.y) + blo(v1.y)) + (blo(v2.y) + blo(v3.y))) + ((blo(v4.y) + blo(v5.y)) + (blo(v6.y) + blo(v7.y)));
    aw += ((bhi(v0.y) + bhi(v1.y)) + (bhi(v2.y) + bhi(v3.y))) + ((bhi(v4.y) + bhi(v5.y)) + (bhi(v6.y) + bhi(v7.y)));
  }
  for (; k < end; ++k) {
    uint2 v = table[(size_t)esrc[k] * 32 + sl];
    ax += blo(v.x); ay += bhi(v.x); az += blo(v.y); aw += bhi(v.y);
  }
  float inv = 1.0f / fmaxf((float)c, 1.0f);
  ((uint2*)(meanL1b + (size_t)n * 64))[sl] =
      make_uint2(pack2(ax * inv, ay * inv), pack2(az * inv, aw * inv));
}

// ---------------------------------------------------------------- layer-2 target aggregation (bf16 tables, fp32 out)
__global__ __launch_bounds__(256) void k_agg_tgt(
    const int* __restrict__ tgt, const int* __restrict__ offs,
    const int* __restrict__ cnt, const int* __restrict__ esrc,
    const unsigned* __restrict__ xu1b, const unsigned* __restrict__ xi1b,
    const float* __restrict__ xu1,
    float* __restrict__ mrev, float* __restrict__ mfol, float* __restrict__ xsel)
{
  int hw = blockIdx.x * 8 + (threadIdx.x >> 5);
  int sl = threadIdx.x & 31;
  int t = hw >> 1, which = hw & 1;
  if (t >= NTGT) return;
  int u = tgt[t];
  int n = (which ? BASE_FOL : BASE_REV) + u;
  const uint2* table = which ? (const uint2*)xu1b : (const uint2*)xi1b;
  int end = offs[n], c = cnt[n], st = end - c;
  float ax = 0.f, ay = 0.f, az = 0.f, aw = 0.f;
  int k = st;
  for (; k + 7 < end; k += 8) {
    int s0 = esrc[k],     s1 = esrc[k + 1], s2 = esrc[k + 2], s3 = esrc[k + 3];
    int s4 = esrc[k + 4], s5 = esrc[k + 5], s6 = esrc[k + 6], s7 = esrc[k + 7];
    uint2 v0 = table[(size_t)s0 * 32 + sl];
    uint2 v1 = table[(size_t)s1 * 32 + sl];
    uint2 v2 = table[(size_t)s2 * 32 + sl];
    uint2 v3 = table[(size_t)s3 * 32 + sl];
    uint2 v4 = table[(size_t)s4 * 32 + sl];
    uint2 v5 = table[(size_t)s5 * 32 + sl];
    uint2 v6 = table[(size_t)s6 * 32 + sl];
    uint2 v7 = table[(size_t)s7 * 32 + sl];
    ax += ((blo(v0.x) + blo(v1.x)) + (blo(v2.x) + blo(v3.x))) + ((blo(v4.x) + blo(v5.x)) + (blo(v6.x) + blo(v7.x)));
    ay += ((bhi(v0.x) + bhi(v1.x)) + (bhi(v2.x) + bhi(v3.x))) + ((bhi(v4.x) + bhi(v5.x)) + (bhi(v6.x) + bhi(v7.x)));
    az += ((blo(v0.y) + blo(v1.y)) + (blo(v2.y) + blo(v3.y))) + ((blo(v4.y) + blo(v5.y)) + (blo(v6.y) + blo(v7.y)));
    aw += ((bhi(v0.y) + bhi(v1.y)) + (bhi(v2.y) + bhi(v3.y))) + ((bhi(v4.y) + bhi(v5.y)) + (bhi(v6.y) + bhi(v7.y)));
  }
  for (; k < end; ++k) {
    uint2 v = table[(size_t)esrc[k] * 32 + sl];
    ax += blo(v.x); ay += bhi(v.x); az += blo(v.y); aw += bhi(v.y);
  }
  float inv = 1.0f / fmaxf((float)c, 1.0f);
  float4 o; o.x = ax * inv; o.y = ay * inv; o.z = az * inv; o.w = aw * inv;
  if (which) {
    ((float4*)mfol)[(size_t)t * 32 + sl] = o;
  } else {
    ((float4*)mrev)[(size_t)t * 32 + sl] = o;
    ((float4*)xsel)[(size_t)t * 32 + sl] = ((const float4*)xu1)[(size_t)u * 32 + sl];
  }
}

// ---------------------------------------------------------------- fused multi-term GEMM + bias + LN + ReLU
// A terms may be fp32 or bf16 (abf16 bit per term); W fp32; fp32 accumulate.
// Optional fp32 and/or bf16 output.
__global__ __launch_bounds__(256) void k_gemm_ln(
    const void* __restrict__ A0, const float* __restrict__ W0,
    const void* __restrict__ A1, const float* __restrict__ W1,
    const void* __restrict__ A2, const float* __restrict__ W2,
    int abf16,
    const float* __restrict__ bias, const float* __restrict__ lng,
    const float* __restrict__ lnb,
    float* __restrict__ out32, unsigned* __restrict__ out16, int M)
{
  const int t = threadIdx.x;
  const int tx = t & 31, ty = t >> 5;
  const int rowbase = blockIdx.x * 64;
  __shared__ float As[32][68];
  __shared__ float Ws[32 * 132];

  float acc[8][4];
  #pragma unroll
  for (int i = 0; i < 8; ++i)
    #pragma unroll
    for (int j = 0; j < 4; ++j) acc[i][j] = 0.f;

  const int arow = t >> 2;
  const int ak8  = (t & 3) * 8;

  #pragma unroll
  for (int term = 0; term < 3; ++term) {
    const void* A = (term == 0) ? A0 : (term == 1) ? A1 : A2;
    const float* W = (term == 0) ? W0 : (term == 1) ? W1 : W2;
    if (A == nullptr) continue;
    bool isb = (abf16 >> term) & 1;
    for (int kc = 0; kc < NH; kc += 32) {
      {
        int gr = rowbase + arow; if (gr > M - 1) gr = M - 1;
        if (isb) {
          const unsigned* Ab = (const unsigned*)A;
          uint4 v = *(const uint4*)(Ab + (size_t)gr * 64 + ((kc + ak8) >> 1));
          As[ak8 + 0][arow] = blo(v.x); As[ak8 + 1][arow] = bhi(v.x);
          As[ak8 + 2][arow] = blo(v.y); As[ak8 + 3][arow] = bhi(v.y);
          As[ak8 + 4][arow] = blo(v.z); As[ak8 + 5][arow] = bhi(v.z);
          As[ak8 + 6][arow] = blo(v.w); As[ak8 + 7][arow] = bhi(v.w);
        } else {
          const float* Af = (const float*)A;
          const float* ap = &Af[(size_t)gr * NH + kc + ak8];
          float4 v0 = *(const float4*)(ap);
          float4 v1 = *(const float4*)(ap + 4);
          As[ak8 + 0][arow] = v0.x; As[ak8 + 1][arow] = v0.y;
          As[ak8 + 2][arow] = v0.z; As[ak8 + 3][arow] = v0.w;
          As[ak8 + 4][arow] = v1.x; As[ak8 + 5][arow] = v1.y;
          As[ak8 + 6][arow] = v1.z; As[ak8 + 7][arow] = v1.w;
        }
      }
      #pragma unroll
      for (int i = 0; i < 4; ++i) {
        int linear = t * 4 + i * 1024;
        int j = linear >> 5, k4 = linear & 31;
        float4 v = *(const float4*)&W[j * NH + kc + k4];
        Ws[(k4 + 0) * 132 + j] = v.x; Ws[(k4 + 1) * 132 + j] = v.y;
        Ws[(k4 + 2) * 132 + j] = v.z; Ws[(k4 + 3) * 132 + j] = v.w;
      }
      __syncthreads();
      #pragma unroll
      for (int kk = 0; kk < 32; ++kk) {
        float4 alo = *(const float4*)&As[kk][ty * 8];
        float4 ahi = *(const float4*)&As[kk][ty * 8 + 4];
        float4 w4  = *(const float4*)&Ws[kk * 132 + tx * 4];
        float ar[8] = {alo.x, alo.y, alo.z, alo.w, ahi.x, ahi.y, ahi.z, ahi.w};
        float wr[4] = {w4.x, w4.y, w4.z, w4.w};
        #pragma unroll
        for (int i = 0; i < 8; ++i)
          #pragma unroll
          for (int j = 0; j < 4; ++j)
            acc[i][j] = fmaf(ar[i], wr[j], acc[i][j]);
      }
      __syncthreads();
    }
  }

  float4 b4 = *(const float4*)&bias[tx * 4];
  float4 g4 = *(const float4*)&lng[tx * 4];
  float4 l4 = *(const float4*)&lnb[tx * 4];
  float bb[4] = {b4.x, b4.y, b4.z, b4.w};
  float gg[4] = {g4.x, g4.y, g4.z, g4.w};
  float ll[4] = {l4.x, l4.y, l4.z, l4.w};

  #pragma unroll
  for (int i = 0; i < 8; ++i) {
    float s = 0.f, ss = 0.f;
    #pragma unroll
    for (int j = 0; j < 4; ++j) {
      float v = acc[i][j] + bb[j];
      acc[i][j] = v;
      s += v; ss += v * v;
    }
    #pragma unroll
    for (int o = 1; o < 32; o <<= 1) { s += __shfl_xor(s, o); ss += __shfl_xor(ss, o); }
    float mu = s * (1.0f / 128.0f);
    float var = ss * (1.0f / 128.0f) - mu * mu;
    float rinv = rsqrtf(var + 1e-5f);
    int gr = rowbase + ty * 8 + i;
    if (gr < M) {
      float4 y;
      y.x = fmaxf((acc[i][0] - mu) * rinv * gg[0] + ll[0], 0.f);
      y.y = fmaxf((acc[i][1] - mu) * rinv * gg[1] + ll[1], 0.f);
      y.z = fmaxf((acc[i][2] - mu) * rinv * gg[2] + ll[2], 0.f);
      y.w = fmaxf((acc[i][3] - mu) * rinv * gg[3] + ll[3], 0.f);
      if (out32) *(float4*)&out32[(size_t)gr * NH + tx * 4] = y;
      if (out16)
        ((uint2*)(out16 + (size_t)gr * 64))[tx] =
            make_uint2(pack2(y.x, y.y), pack2(y.z, y.w));
    }
  }
}

// ---------------------------------------------------------------- final MLP: relu(h@W1.T+b1)@W2.T+b2
__global__ __launch_bounds__(256) void k_mlp(
    const float* __restrict__ h2, const float* __restrict__ W1,
    const float* __restrict__ b1, const float* __restrict__ W2,
    const float* __restrict__ b2, float* __restrict__ out)
{
  __shared__ float W1s[64 * 129];
  __shared__ float b1s[64];
  __shared__ float W2s[64];
  __shared__ float sx[4][128];
  int t = threadIdx.x;
  #pragma unroll
  for (int i = 0; i < 32; ++i) {
    int idx = t + 256 * i;
    int j = idx >> 7, k = idx & 127;
    W1s[j * 129 + k] = W1[idx];
  }
  if (t < 64) { b1s[t] = b1[t]; W2s[t] = W2[t]; }
  __syncthreads();
  int w = t >> 6, lane = t & 63;
  float b2v = b2[0];
  for (int it = 0; it < 8; ++it) {
    int r = blockIdx.x * 32 + it * 4 + w;
    sx[w][lane]      = h2[(size_t)r * NH + lane];
    sx[w][lane + 64] = h2[(size_t)r * NH + lane + 64];
    __syncthreads();
    float h = b1s[lane];
    #pragma unroll
    for (int k = 0; k < 128; ++k) h = fmaf(sx[w][k], W1s[lane * 129 + k], h);
    h = fmaxf(h, 0.f);
    float p = h * W2s[lane];
    #pragma unroll
    for (int o = 32; o > 0; o >>= 1) p += __shfl_down(p, o);
    if (lane == 0) out[r] = p + b2v;
    __syncthreads();
  }
}

// ---------------------------------------------------------------- launch
extern "C" void kernel_launch(void* const* d_in, const int* in_sizes, int n_in,
                              void* d_out, int out_size, void* d_ws, size_t ws_size,
                              hipStream_t stream)
{
  const float* emb_user = (const float*)d_in[0];
  const float* emb_item = (const float*)d_in[1];
  const float* Wl   = (const float*)d_in[2];   // [2,3,128,128]
  const float* bl   = (const float*)d_in[3];   // [2,3,128]
  const float* Wr   = (const float*)d_in[4];   // [2,3,128,128]
  const float* ln_g = (const float*)d_in[5];   // [2,2,128]
  const float* ln_b = (const float*)d_in[6];   // [2,2,128]
  const float* W1   = (const float*)d_in[7];   // [64,128]
  const float* b1   = (const float*)d_in[8];   // [64]
  const float* W2   = (const float*)d_in[9];   // [1,64]
  const float* b2   = (const float*)d_in[10];  // [1]
  const int* src_buys = (const int*)d_in[11];
  const int* dst_buys = (const int*)d_in[12];
  const int* src_rev  = (const int*)d_in[13];
  const int* dst_rev  = (const int*)d_in[14];
  const int* src_fol  = (const int*)d_in[15];
  const int* dst_fol  = (const int*)d_in[16];
  const int* tgt      = (const int*)d_in[17];
  float* outp = (float*)d_out;

  char* wp = (char*)d_ws;
  size_t ob = 0;
  auto take = [&](size_t bytes) -> void* {
    void* p = wp + ob;
    ob += (bytes + 255) & ~(size_t)255;
    return p;
  };
  int*      cnt     = (int*)     take((size_t)NNODE * 4);
  int*      offs    = (int*)     take((size_t)NNODE * 4);
  int*      cntBB   = (int*)     take((size_t)NRUN * 4);
  int*      sscan   = (int*)     take((size_t)(NRUN + 1) * 4);
  int*      partial = (int*)     take((size_t)NSCANB * 4);
  int*      pbase   = (int*)     take((size_t)NSCANB * 4);
  int*      esrc    = (int*)     take((size_t)3 * NEDGE * 4);
  float*    Wrc     = (float*)   take((size_t)2 * NH * NH * 4);
  float*    bc      = (float*)   take((size_t)2 * NH * 4);
  unsigned* meanL1b = (unsigned*)take((size_t)NNODE * NH * 2);    // bf16
  unsigned* ub      = (unsigned*)take((size_t)N_USERS * NH * 2);  // bf16 emb_user
  unsigned* ib      = (unsigned*)take((size_t)N_ITEMS * NH * 2);  // bf16 emb_item
  float*    xu1     = (float*)   take((size_t)N_USERS * NH * 4);
  unsigned* xu1b    = (unsigned*)take((size_t)N_USERS * NH * 2);  // bf16 copy
  unsigned* xi1b    = (unsigned*)take((size_t)N_ITEMS * NH * 2);  // bf16 only
  float*    mrev2   = (float*)   take((size_t)NTGT * NH * 4);
  float*    mfol2   = (float*)   take((size_t)NTGT * NH * 4);
  float*    xsel2   = (float*)   take((size_t)NTGT * NH * 4);
  float*    h2      = (float*)   take((size_t)NTGT * NH * 4);
  // binned edge buffer (9.6 MB) aliases meanL1b (64 MB): consumed by k_csr
  // before k_agg1 writes meanL1b.
  int*      binned  = (int*)meanL1b;

  k_combine<<<(2 * NH * NH + 2 * NH + 255) / 256, 256, 0, stream>>>(Wr, bl, Wrc, bc);
  k_tobf16<<<N_USERS * NH / 8 / 256, 256, 0, stream>>>(emb_user, ub);
  k_tobf16<<<N_ITEMS * NH / 8 / 256, 256, 0, stream>>>(emb_item, ib);
  k_pcount<<<NBLK, 256, 0, stream>>>(dst_buys, dst_rev, dst_fol, cntBB);
  k_scanA<<<NSCANB, 256, 0, stream>>>(cntBB, partial);
  k_scanB<<<1, 256, 0, stream>>>(partial, pbase);
  k_scanC<<<NSCANB, 256, 0, stream>>>(cntBB, pbase, sscan);
  k_pfill<<<NBLK, 256, 0, stream>>>(
      src_buys, dst_buys, src_rev, dst_rev, src_fol, dst_fol, sscan, binned);
  k_csr<<<NBUCK, 256, 0, stream>>>(binned, sscan, cnt, offs, esrc);
  k_agg1<<<(NNODE + 7) / 8, 256, 0, stream>>>(offs, cnt, esrc, ub, ib, meanL1b);

  // layer-1 item: relu(LN(mean_buys@Wl00.T + xi0@Wr00.T + bl00)) -> bf16 only
  k_gemm_ln<<<(N_ITEMS + 63) / 64, 256, 0, stream>>>(
      meanL1b, Wl + 0 * NH * NH,
      emb_item, Wr + 0 * NH * NH,
      nullptr, nullptr, /*abf16=*/0b001,
      bl + 0 * NH, ln_g + 1 * NH, ln_b + 1 * NH, nullptr, xi1b, N_ITEMS);

  // layer-1 user: relu(LN(mean_rev@Wl01.T + mean_fol@Wl02.T + xu0@(Wr01+Wr02).T + bl01+bl02))
  k_gemm_ln<<<(N_USERS + 63) / 64, 256, 0, stream>>>(
      meanL1b + (size_t)BASE_REV * 64, Wl + 1 * NH * NH,
      meanL1b + (size_t)BASE_FOL * 64, Wl + 2 * NH * NH,
      emb_user, Wrc, /*abf16=*/0b011,
      bc, ln_g + 0 * NH, ln_b + 0 * NH, xu1, xu1b, N_USERS);

  // layer-2 aggregation at targets only (item update is dead code)
  k_agg_tgt<<<(2 * NTGT + 7) / 8, 256, 0, stream>>>(
      tgt, offs, cnt, esrc, xu1b, xi1b, xu1, mrev2, mfol2, xsel2);

  // layer-2 user at targets (all-fp32 A)
  k_gemm_ln<<<(NTGT + 63) / 64, 256, 0, stream>>>(
      mrev2, Wl + (1 * 3 + 1) * NH * NH,
      mfol2, Wl + (1 * 3 + 2) * NH * NH,
      xsel2, Wrc + NH * NH, /*abf16=*/0,
      bc + NH, ln_g + 2 * NH, ln_b + 2 * NH, h2, nullptr, NTGT);

  // final MLP
  k_mlp<<<NTGT / 32, 256, 0, stream>>>(h2, W1, b1, W2, b2, outp);
}

// Round 6
// 494.619 us; speedup vs baseline: 1.2860x; 1.2860x over previous
//
#include <hip/hip_runtime.h>

#define N_USERS 100000
#define N_ITEMS 50000
#define NEDGE   800000
#define NH      128
#define NTGT    8192
#define NNODE   250000      // 50K item slots (buys) + 100K user (rev) + 100K user (fol)
#define BASE_REV 50000
#define BASE_FOL 150000
#define NBUCK   588         // 196 buys (256 nodes) + 196 rev (512) + 196 fol (512)
#define NBLK    384         // binning blocks
#define NPB     6250        // edges per binning block: 384*6250 = 2400000 exactly
#define NRUN    (NBUCK * NBLK)        // 225792 per-(bucket,block) runs
#define NSCANB  441                   // 225792 / 512 exactly

typedef __attribute__((ext_vector_type(8))) short short8;
typedef __attribute__((ext_vector_type(4))) float f32x4;

// ---------------------------------------------------------------- bf16 helpers (RNE, manual)
__device__ __forceinline__ unsigned rne_hi(float f) {
  unsigned u = __float_as_uint(f);
  u += 0x7FFFu + ((u >> 16) & 1u);
  return u & 0xFFFF0000u;
}
__device__ __forceinline__ unsigned pack2(float f0, float f1) {
  return (rne_hi(f0) >> 16) | rne_hi(f1);   // low ushort = f0, high = f1
}
__device__ __forceinline__ float blo(unsigned u) { return __uint_as_float(u << 16); }
__device__ __forceinline__ float bhi(unsigned u) { return __uint_as_float(u & 0xFFFF0000u); }

__device__ __forceinline__ int bucket_of(int n) {
  return (n < BASE_REV) ? (n >> 8)
       : (n < BASE_FOL) ? 196 + ((n - BASE_REV) >> 9)
                        : 392 + ((n - BASE_FOL) >> 9);
}

// ---------------------------------------------------------------- fp32 -> bf16 conversion (8 elems/thread)
__global__ __launch_bounds__(256) void k_tobf16(const float* __restrict__ x,
                                                unsigned* __restrict__ y)
{
  int i = blockIdx.x * 256 + threadIdx.x;
  const float4* xp = (const float4*)x;
  float4 a = xp[(size_t)i * 2];
  float4 b = xp[(size_t)i * 2 + 1];
  ((uint4*)y)[i] = make_uint4(pack2(a.x, a.y), pack2(a.z, a.w),
                              pack2(b.x, b.y), pack2(b.z, b.w));
}

// ---------------------------------------------------------------- pass A: per-(bucket,block) histogram, LDS only
__global__ __launch_bounds__(256) void k_pcount(
    const int* __restrict__ db, const int* __restrict__ dr,
    const int* __restrict__ df, int* __restrict__ cntBB)
{
  __shared__ int h[NBUCK];
  int t = threadIdx.x, blk = blockIdx.x;
  for (int j = t; j < NBUCK; j += 256) h[j] = 0;
  __syncthreads();
  int ebase = blk * NPB;
  for (int i = t; i < NPB; i += 256) {
    int e = ebase + i, n;
    if (e < NEDGE)          n = db[e];
    else if (e < 2 * NEDGE) n = BASE_REV + dr[e - NEDGE];
    else                    n = BASE_FOL + df[e - 2 * NEDGE];
    atomicAdd(&h[bucket_of(n)], 1);
  }
  __syncthreads();
  for (int j = t; j < NBUCK; j += 256) cntBB[j * NBLK + blk] = h[j];
}

// ---------------------------------------------------------------- scan of 225792 counts (3 tiny kernels)
__global__ __launch_bounds__(256) void k_scanA(const int* __restrict__ cntBB,
                                               int* __restrict__ partial)
{
  int t = threadIdx.x;
  int base = blockIdx.x * 512;
  int s = cntBB[base + t] + cntBB[base + 256 + t];
  __shared__ int red[256];
  red[t] = s; __syncthreads();
  for (int d = 128; d > 0; d >>= 1) { if (t < d) red[t] += red[t + d]; __syncthreads(); }
  if (t == 0) partial[blockIdx.x] = red[0];
}

__global__ __launch_bounds__(256) void k_scanB(const int* __restrict__ partial,
                                               int* __restrict__ pbase)
{
  __shared__ int carry;
  __shared__ int wsum[4];
  int t = threadIdx.x, lane = t & 63, w = t >> 6;
  if (t == 0) carry = 0;
  __syncthreads();
  for (int base = 0; base < NSCANB; base += 256) {
    int orig = (base + t < NSCANB) ? partial[base + t] : 0;
    int v = orig;
    #pragma unroll
    for (int o = 1; o < 64; o <<= 1) { int u = __shfl_up(v, o); if (lane >= o) v += u; }
    if (lane == 63) wsum[w] = v;
    __syncthreads();
    int wb = 0;
    for (int i = 0; i < w; ++i) wb += wsum[i];
    int excl = carry + wb + v - orig;
    if (base + t < NSCANB) pbase[base + t] = excl;
    __syncthreads();
    if (t == 255) carry = excl + orig;
    __syncthreads();
  }
}

__global__ __launch_bounds__(256) void k_scanC(const int* __restrict__ cntBB,
                                               const int* __restrict__ pbase,
                                               int* __restrict__ sscan)
{
  int t = threadIdx.x, blk = blockIdx.x;
  int base = blk * 512;
  int a0 = cntBB[base + t * 2], a1 = cntBB[base + t * 2 + 1];
  int sum = a0 + a1;
  int lane = t & 63, w = t >> 6;
  int v = sum;
  #pragma unroll
  for (int o = 1; o < 64; o <<= 1) { int u = __shfl_up(v, o); if (lane >= o) v += u; }
  __shared__ int wsum[4];
  if (lane == 63) wsum[w] = v;
  __syncthreads();
  int wb = 0;
  for (int i = 0; i < w; ++i) wb += wsum[i];
  int excl = wb + v - sum;
  int P = pbase[blk];
  sscan[base + t * 2]     = P + excl;
  sscan[base + t * 2 + 1] = P + excl + a0;
  if (blk == NSCANB - 1 && t == 255)
    sscan[NRUN] = P + wsum[0] + wsum[1] + wsum[2] + wsum[3];   // == 3*NEDGE
}

// ---------------------------------------------------------------- pass B: scatter into pre-reserved runs (LDS cursors only)
__global__ __launch_bounds__(256) void k_pfill(
    const int* __restrict__ sb, const int* __restrict__ db,
    const int* __restrict__ sr, const int* __restrict__ dr,
    const int* __restrict__ sf, const int* __restrict__ df,
    const int* __restrict__ sscan, int* __restrict__ binned)
{
  __shared__ int cur[NBUCK];
  int t = threadIdx.x, blk = blockIdx.x;
  for (int j = t; j < NBUCK; j += 256) cur[j] = sscan[j * NBLK + blk];
  __syncthreads();
  int ebase = blk * NPB;
  for (int i = t; i < NPB; i += 256) {
    int e = ebase + i, n, s;
    if (e < NEDGE)          { n = db[e];                      s = sb[e]; }
    else if (e < 2 * NEDGE) { n = BASE_REV + dr[e - NEDGE];   s = sr[e - NEDGE]; }
    else                    { n = BASE_FOL + df[e - 2*NEDGE]; s = sf[e - 2*NEDGE]; }
    int b = bucket_of(n);
    int local = (n < BASE_REV) ? (n & 255)
              : (n < BASE_FOL) ? ((n - BASE_REV) & 511)
                               : ((n - BASE_FOL) & 511);
    int pos = atomicAdd(&cur[b], 1);
    binned[pos] = (local << 17) | s;
  }
}

// ---------------------------------------------------------------- pass C: per-bucket CSR build (1 block / bucket)
__global__ __launch_bounds__(256) void k_csr(
    const int* __restrict__ binned, const int* __restrict__ sscan,
    int* __restrict__ cnt, int* __restrict__ offs, int* __restrict__ esrc)
{
  int b = blockIdx.x;
  int n0, S;
  if (b < 196)      { n0 = b * 256;                    S = min(256, BASE_REV - n0); }
  else if (b < 392) { n0 = BASE_REV + (b - 196) * 512; S = min(512, BASE_FOL - n0); }
  else              { n0 = BASE_FOL + (b - 392) * 512; S = min(512, NNODE - n0); }
  int e0 = sscan[b * NBLK];
  int e1 = sscan[(b + 1) * NBLK];
  int t = threadIdx.x;
  __shared__ int h[512], fl[512];
  __shared__ int wsum[4];
  h[t] = 0; h[t + 256] = 0;
  __syncthreads();
  for (int e = e0 + t; e < e1; e += 256)
    atomicAdd(&h[binned[e] >> 17], 1);
  __syncthreads();
  int a0 = h[t * 2], a1 = h[t * 2 + 1];
  int v = a0 + a1;
  int lane = t & 63, w = t >> 6;
  #pragma unroll
  for (int o = 1; o < 64; o <<= 1) { int u = __shfl_up(v, o); if (lane >= o) v += u; }
  if (lane == 63) wsum[w] = v;
  __syncthreads();
  int wb = 0;
  for (int i = 0; i < w; ++i) wb += wsum[i];
  int excl = wb + v - (a0 + a1);
  fl[t * 2]     = e0 + excl;
  fl[t * 2 + 1] = e0 + excl + a0;
  if (t * 2 < S)     { cnt[n0 + t * 2]     = a0; offs[n0 + t * 2]     = e0 + excl + a0; }
  if (t * 2 + 1 < S) { cnt[n0 + t * 2 + 1] = a1; offs[n0 + t * 2 + 1] = e0 + excl + a0 + a1; }
  __syncthreads();
  for (int e = e0 + t; e < e1; e += 256) {
    int v2 = binned[e];
    int p = atomicAdd(&fl[v2 >> 17], 1);
    esrc[p] = v2 & 0x1FFFF;
  }
}

// ---------------------------------------------------------------- combine Wr1+Wr2, bl1+bl2
__global__ __launch_bounds__(256) void k_combine(
    const float* __restrict__ Wr, const float* __restrict__ bl,
    float* __restrict__ Wrc, float* __restrict__ bc)
{
  int i = blockIdx.x * 256 + threadIdx.x;
  if (i < 2 * NH * NH) {
    int l = i >> 14, r = i & (NH * NH - 1);
    Wrc[i] = Wr[(l * 3 + 1) * NH * NH + r] + Wr[(l * 3 + 2) * NH * NH + r];
  } else {
    int j = i - 2 * NH * NH;
    if (j < 2 * NH) {
      int l = j >> 7, r = j & (NH - 1);
      bc[j] = bl[(l * 3 + 1) * NH + r] + bl[(l * 3 + 2) * NH + r];
    }
  }
}

// ---------------------------------------------------------------- layer-1 mean aggregation (bf16 tables, bf16 out)
__global__ __launch_bounds__(256) void k_agg1(
    const int* __restrict__ offs, const int* __restrict__ cnt,
    const int* __restrict__ esrc,
    const unsigned* __restrict__ ub, const unsigned* __restrict__ ib,
    unsigned* __restrict__ meanL1b)
{
  int n = blockIdx.x * 8 + (threadIdx.x >> 5);
  int sl = threadIdx.x & 31;
  if (n >= NNODE) return;
  const uint2* table = (n < BASE_REV) ? (const uint2*)ub
                     : (n < BASE_FOL) ? (const uint2*)ib
                                      : (const uint2*)ub;
  int end = offs[n], c = cnt[n], st = end - c;
  float ax = 0.f, ay = 0.f, az = 0.f, aw = 0.f;
  int k = st;
  for (; k + 7 < end; k += 8) {
    int s0 = esrc[k],     s1 = esrc[k + 1], s2 = esrc[k + 2], s3 = esrc[k + 3];
    int s4 = esrc[k + 4], s5 = esrc[k + 5], s6 = esrc[k + 6], s7 = esrc[k + 7];
    uint2 v0 = table[(size_t)s0 * 32 + sl];
    uint2 v1 = table[(size_t)s1 * 32 + sl];
    uint2 v2 = table[(size_t)s2 * 32 + sl];
    uint2 v3 = table[(size_t)s3 * 32 + sl];
    uint2 v4 = table[(size_t)s4 * 32 + sl];
    uint2 v5 = table[(size_t)s5 * 32 + sl];
    uint2 v6 = table[(size_t)s6 * 32 + sl];
    uint2 v7 = table[(size_t)s7 * 32 + sl];
    ax += ((blo(v0.x) + blo(v1.x)) + (blo(v2.x) + blo(v3.x))) + ((blo(v4.x) + blo(v5.x)) + (blo(v6.x) + blo(v7.x)));
    ay += ((bhi(v0.x) + bhi(v1.x)) + (bhi(v2.x) + bhi(v3.x))) + ((bhi(v4.x) + bhi(v5.x)) + (bhi(v6.x) + bhi(v7.x)));
    az += ((blo(v0.y) + blo(v1.y)) + (blo(v2.y) + blo(v3.y))) + ((blo(v4.y) + blo(v5.y)) + (blo(v6.y) + blo(v7.y)));
    aw += ((bhi(v0.y) + bhi(v1.y)) + (bhi(v2.y) + bhi(v3.y))) + ((bhi(v4.y) + bhi(v5.y)) + (bhi(v6.y) + bhi(v7.y)));
  }
  for (; k < end; ++k) {
    uint2 v = table[(size_t)esrc[k] * 32 + sl];
    ax += blo(v.x); ay += bhi(v.x); az += blo(v.y); aw += bhi(v.y);
  }
  float inv = 1.0f / fmaxf((float)c, 1.0f);
  ((uint2*)(meanL1b + (size_t)n * 64))[sl] =
      make_uint2(pack2(ax * inv, ay * inv), pack2(az * inv, aw * inv));
}

// ---------------------------------------------------------------- layer-2 target aggregation (bf16 tables, fp32 out)
__global__ __launch_bounds__(256) void k_agg_tgt(
    const int* __restrict__ tgt, const int* __restrict__ offs,
    const int* __restrict__ cnt, const int* __restrict__ esrc,
    const unsigned* __restrict__ xu1b, const unsigned* __restrict__ xi1b,
    float* __restrict__ mrev, float* __restrict__ mfol, float* __restrict__ xsel)
{
  int hw = blockIdx.x * 8 + (threadIdx.x >> 5);
  int sl = threadIdx.x & 31;
  int t = hw >> 1, which = hw & 1;
  if (t >= NTGT) return;
  int u = tgt[t];
  int n = (which ? BASE_FOL : BASE_REV) + u;
  const uint2* table = which ? (const uint2*)xu1b : (const uint2*)xi1b;
  int end = offs[n], c = cnt[n], st = end - c;
  float ax = 0.f, ay = 0.f, az = 0.f, aw = 0.f;
  int k = st;
  for (; k + 7 < end; k += 8) {
    int s0 = esrc[k],     s1 = esrc[k + 1], s2 = esrc[k + 2], s3 = esrc[k + 3];
    int s4 = esrc[k + 4], s5 = esrc[k + 5], s6 = esrc[k + 6], s7 = esrc[k + 7];
    uint2 v0 = table[(size_t)s0 * 32 + sl];
    uint2 v1 = table[(size_t)s1 * 32 + sl];
    uint2 v2 = table[(size_t)s2 * 32 + sl];
    uint2 v3 = table[(size_t)s3 * 32 + sl];
    uint2 v4 = table[(size_t)s4 * 32 + sl];
    uint2 v5 = table[(size_t)s5 * 32 + sl];
    uint2 v6 = table[(size_t)s6 * 32 + sl];
    uint2 v7 = table[(size_t)s7 * 32 + sl];
    ax += ((blo(v0.x) + blo(v1.x)) + (blo(v2.x) + blo(v3.x))) + ((blo(v4.x) + blo(v5.x)) + (blo(v6.x) + blo(v7.x)));
    ay += ((bhi(v0.x) + bhi(v1.x)) + (bhi(v2.x) + bhi(v3.x))) + ((bhi(v4.x) + bhi(v5.x)) + (bhi(v6.x) + bhi(v7.x)));
    az += ((blo(v0.y) + blo(v1.y)) + (blo(v2.y) + blo(v3.y))) + ((blo(v4.y) + blo(v5.y)) + (blo(v6.y) + blo(v7.y)));
    aw += ((bhi(v0.y) + bhi(v1.y)) + (bhi(v2.y) + bhi(v3.y))) + ((bhi(v4.y) + bhi(v5.y)) + (bhi(v6.y) + bhi(v7.y)));
  }
  for (; k < end; ++k) {
    uint2 v = table[(size_t)esrc[k] * 32 + sl];
    ax += blo(v.x); ay += bhi(v.x); az += blo(v.y); aw += bhi(v.y);
  }
  float inv = 1.0f / fmaxf((float)c, 1.0f);
  float4 o; o.x = ax * inv; o.y = ay * inv; o.z = az * inv; o.w = aw * inv;
  if (which) {
    ((float4*)mfol)[(size_t)t * 32 + sl] = o;
  } else {
    ((float4*)mrev)[(size_t)t * 32 + sl] = o;
    uint2 xv = ((const uint2*)xu1b)[(size_t)u * 32 + sl];
    float4 xo; xo.x = blo(xv.x); xo.y = bhi(xv.x); xo.z = blo(xv.y); xo.w = bhi(xv.y);
    ((float4*)xsel)[(size_t)t * 32 + sl] = xo;
  }
}

// ---------------------------------------------------------------- MFMA layer-1 GEMM + bias + LN + ReLU (bf16 in, bf16 out)
// out[r][c] = relu(LN_row(sum_t A_t[r][:].W_t[c][:] + bias[c]))
// A row-major [M][128] bf16; W row-major [128][128] bf16 (out = A @ W^T).
// Block: 4 waves x 32 rows = 128 rows. Per wave: 2 m-tiles x 8 n-tiles,
// frags loaded direct from global (contiguous 16B; A/B layout A[m=lane&15][k=quad*8+j]).
// C/D: col=lane&15, row=quad*4+reg -> LN via intra-quad shfl_xor(1,2,4,8).
__global__ __launch_bounds__(256) void k_mfma_ln(
    const unsigned short* __restrict__ A0, const unsigned short* __restrict__ W0,
    const unsigned short* __restrict__ A1, const unsigned short* __restrict__ W1,
    const unsigned short* __restrict__ A2, const unsigned short* __restrict__ W2,
    const float* __restrict__ bias, const float* __restrict__ lng,
    const float* __restrict__ lnb, unsigned short* __restrict__ out, int M)
{
  __shared__ unsigned short ytile[4][32][132];   // stride 132 (8B-aligned rows, bank-spread)
  const int t = threadIdx.x;
  const int wv = t >> 6, lane = t & 63;
  const int quad = lane >> 4, c0 = lane & 15;
  const int m0 = blockIdx.x * 128 + wv * 32;
  const int ko = quad * 8;

  f32x4 acc[2][8];
  #pragma unroll
  for (int i = 0; i < 2; ++i)
    #pragma unroll
    for (int j = 0; j < 8; ++j) acc[i][j] = (f32x4){0.f, 0.f, 0.f, 0.f};

  int gr0 = m0 + c0;      if (gr0 > M - 1) gr0 = M - 1;
  int gr1 = m0 + 16 + c0; if (gr1 > M - 1) gr1 = M - 1;

  #pragma unroll
  for (int term = 0; term < 3; ++term) {
    const unsigned short* A = (term == 0) ? A0 : (term == 1) ? A1 : A2;
    const unsigned short* W = (term == 0) ? W0 : (term == 1) ? W1 : W2;
    if (!A) continue;
    #pragma unroll
    for (int kc = 0; kc < NH; kc += 32) {
      short8 b[8];
      #pragma unroll
      for (int j = 0; j < 8; ++j)
        b[j] = *(const short8*)(W + (size_t)(16 * j + c0) * NH + kc + ko);
      short8 a0 = *(const short8*)(A + (size_t)gr0 * NH + kc + ko);
      short8 a1 = *(const short8*)(A + (size_t)gr1 * NH + kc + ko);
      #pragma unroll
      for (int j = 0; j < 8; ++j) {
        acc[0][j] = __builtin_amdgcn_mfma_f32_16x16x32_bf16(a0, b[j], acc[0][j], 0, 0, 0);
        acc[1][j] = __builtin_amdgcn_mfma_f32_16x16x32_bf16(a1, b[j], acc[1][j], 0, 0, 0);
      }
    }
  }

  float bb[8], gg[8], ll[8];
  #pragma unroll
  for (int j = 0; j < 8; ++j) {
    bb[j] = bias[16 * j + c0]; gg[j] = lng[16 * j + c0]; ll[j] = lnb[16 * j + c0];
  }

  #pragma unroll
  for (int i = 0; i < 2; ++i) {
    #pragma unroll
    for (int r = 0; r < 4; ++r) {
      float v[8]; float s = 0.f, ss = 0.f;
      #pragma unroll
      for (int j = 0; j < 8; ++j) {
        float x = acc[i][j][r] + bb[j];
        v[j] = x; s += x; ss += x * x;
      }
      #pragma unroll
      for (int o = 1; o < 16; o <<= 1) { s += __shfl_xor(s, o); ss += __shfl_xor(ss, o); }
      float mu = s * (1.0f / 128.0f);
      float var = ss * (1.0f / 128.0f) - mu * mu;
      float rinv = rsqrtf(var + 1e-5f);
      int rl = 16 * i + quad * 4 + r;
      #pragma unroll
      for (int j = 0; j < 8; ++j) {
        float y = fmaxf((v[j] - mu) * rinv * gg[j] + ll[j], 0.f);
        ytile[wv][rl][16 * j + c0] = (unsigned short)(rne_hi(y) >> 16);
      }
    }
  }
  __syncthreads();
  // coalesced copy out: 128 rows x 128 bf16, uint2 (4 elems) per thread-iter
  #pragma unroll
  for (int it = 0; it < 16; ++it) {
    int idx = it * 256 + t;
    int row = idx >> 5, c4 = (idx & 31) * 4;
    int gr = blockIdx.x * 128 + row;
    if (gr < M)
      *(uint2*)(out + (size_t)gr * NH + c4) = *(const uint2*)&ytile[row >> 5][row & 31][c4];
  }
}

// ---------------------------------------------------------------- fp32 GEMM + bias + LN + ReLU (target layer only)
__global__ __launch_bounds__(256) void k_gemm_ln(
    const float* __restrict__ A0, const float* __restrict__ W0,
    const float* __restrict__ A1, const float* __restrict__ W1,
    const float* __restrict__ A2, const float* __restrict__ W2,
    const float* __restrict__ bias, const float* __restrict__ lng,
    const float* __restrict__ lnb, float* __restrict__ out, int M)
{
  const int t = threadIdx.x;
  const int tx = t & 31, ty = t >> 5;
  const int rowbase = blockIdx.x * 64;
  __shared__ float As[32][68];
  __shared__ float Ws[32 * 132];

  float acc[8][4];
  #pragma unroll
  for (int i = 0; i < 8; ++i)
    #pragma unroll
    for (int j = 0; j < 4; ++j) acc[i][j] = 0.f;

  const int arow = t >> 2;
  const int ak8  = (t & 3) * 8;

  #pragma unroll
  for (int term = 0; term < 3; ++term) {
    const float* A = (term == 0) ? A0 : (term == 1) ? A1 : A2;
    const float* W = (term == 0) ? W0 : (term == 1) ? W1 : W2;
    if (A == nullptr) continue;
    for (int kc = 0; kc < NH; kc += 32) {
      {
        int gr = rowbase + arow; if (gr > M - 1) gr = M - 1;
        const float* ap = &A[(size_t)gr * NH + kc + ak8];
        float4 v0 = *(const float4*)(ap);
        float4 v1 = *(const float4*)(ap + 4);
        As[ak8 + 0][arow] = v0.x; As[ak8 + 1][arow] = v0.y;
        As[ak8 + 2][arow] = v0.z; As[ak8 + 3][arow] = v0.w;
        As[ak8 + 4][arow] = v1.x; As[ak8 + 5][arow] = v1.y;
        As[ak8 + 6][arow] = v1.z; As[ak8 + 7][arow] = v1.w;
      }
      #pragma unroll
      for (int i = 0; i < 4; ++i) {
        int linear = t * 4 + i * 1024;
        int j = linear >> 5, k4 = linear & 31;
        float4 v = *(const float4*)&W[j * NH + kc + k4];
        Ws[(k4 + 0) * 132 + j] = v.x; Ws[(k4 + 1) * 132 + j] = v.y;
        Ws[(k4 + 2) * 132 + j] = v.z; Ws[(k4 + 3) * 132 + j] = v.w;
      }
      __syncthreads();
      #pragma unroll
      for (int kk = 0; kk < 32; ++kk) {
        float4 alo = *(const float4*)&As[kk][ty * 8];
        float4 ahi = *(const float4*)&As[kk][ty * 8 + 4];
        float4 w4  = *(const float4*)&Ws[kk * 132 + tx * 4];
        float ar[8] = {alo.x, alo.y, alo.z, alo.w, ahi.x, ahi.y, ahi.z, ahi.w};
        float wr[4] = {w4.x, w4.y, w4.z, w4.w};
        #pragma unroll
        for (int i = 0; i < 8; ++i)
          #pragma unroll
          for (int j = 0; j < 4; ++j)
            acc[i][j] = fmaf(ar[i], wr[j], acc[i][j]);
      }
      __syncthreads();
    }
  }

  float4 b4 = *(const float4*)&bias[tx * 4];
  float4 g4 = *(const float4*)&lng[tx * 4];
  float4 l4 = *(const float4*)&lnb[tx * 4];
  float bb[4] = {b4.x, b4.y, b4.z, b4.w};
  float gg[4] = {g4.x, g4.y, g4.z, g4.w};
  float ll[4] = {l4.x, l4.y, l4.z, l4.w};

  #pragma unroll
  for (int i = 0; i < 8; ++i) {
    float s = 0.f, ss = 0.f;
    #pragma unroll
    for (int j = 0; j < 4; ++j) {
      float v = acc[i][j] + bb[j];
      acc[i][j] = v;
      s += v; ss += v * v;
    }
    #pragma unroll
    for (int o = 1; o < 32; o <<= 1) { s += __shfl_xor(s, o); ss += __shfl_xor(ss, o); }
    float mu = s * (1.0f / 128.0f);
    float var = ss * (1.0f / 128.0f) - mu * mu;
    float rinv = rsqrtf(var + 1e-5f);
    int gr = rowbase + ty * 8 + i;
    if (gr < M) {
      float4 y;
      y.x = fmaxf((acc[i][0] - mu) * rinv * gg[0] + ll[0], 0.f);
      y.y = fmaxf((acc[i][1] - mu) * rinv * gg[1] + ll[1], 0.f);
      y.z = fmaxf((acc[i][2] - mu) * rinv * gg[2] + ll[2], 0.f);
      y.w = fmaxf((acc[i][3] - mu) * rinv * gg[3] + ll[3], 0.f);
      *(float4*)&out[(size_t)gr * NH + tx * 4] = y;
    }
  }
}

// ---------------------------------------------------------------- final MLP: relu(h@W1.T+b1)@W2.T+b2
__global__ __launch_bounds__(256) void k_mlp(
    const float* __restrict__ h2, const float* __restrict__ W1,
    const float* __restrict__ b1, const float* __restrict__ W2,
    const float* __restrict__ b2, float* __restrict__ out)
{
  __shared__ float W1s[64 * 129];
  __shared__ float b1s[64];
  __shared__ float W2s[64];
  __shared__ float sx[4][128];
  int t = threadIdx.x;
  #pragma unroll
  for (int i = 0; i < 32; ++i) {
    int idx = t + 256 * i;
    int j = idx >> 7, k = idx & 127;
    W1s[j * 129 + k] = W1[idx];
  }
  if (t < 64) { b1s[t] = b1[t]; W2s[t] = W2[t]; }
  __syncthreads();
  int w = t >> 6, lane = t & 63;
  float b2v = b2[0];
  for (int it = 0; it < 8; ++it) {
    int r = blockIdx.x * 32 + it * 4 + w;
    sx[w][lane]      = h2[(size_t)r * NH + lane];
    sx[w][lane + 64] = h2[(size_t)r * NH + lane + 64];
    __syncthreads();
    float h = b1s[lane];
    #pragma unroll
    for (int k = 0; k < 128; ++k) h = fmaf(sx[w][k], W1s[lane * 129 + k], h);
    h = fmaxf(h, 0.f);
    float p = h * W2s[lane];
    #pragma unroll
    for (int o = 32; o > 0; o >>= 1) p += __shfl_down(p, o);
    if (lane == 0) out[r] = p + b2v;
    __syncthreads();
  }
}

// ---------------------------------------------------------------- launch
extern "C" void kernel_launch(void* const* d_in, const int* in_sizes, int n_in,
                              void* d_out, int out_size, void* d_ws, size_t ws_size,
                              hipStream_t stream)
{
  const float* emb_user = (const float*)d_in[0];
  const float* emb_item = (const float*)d_in[1];
  const float* Wl   = (const float*)d_in[2];   // [2,3,128,128]
  const float* bl   = (const float*)d_in[3];   // [2,3,128]
  const float* Wr   = (const float*)d_in[4];   // [2,3,128,128]
  const float* ln_g = (const float*)d_in[5];   // [2,2,128]
  const float* ln_b = (const float*)d_in[6];   // [2,2,128]
  const float* W1   = (const float*)d_in[7];   // [64,128]
  const float* b1   = (const float*)d_in[8];   // [64]
  const float* W2   = (const float*)d_in[9];   // [1,64]
  const float* b2   = (const float*)d_in[10];  // [1]
  const int* src_buys = (const int*)d_in[11];
  const int* dst_buys = (const int*)d_in[12];
  const int* src_rev  = (const int*)d_in[13];
  const int* dst_rev  = (const int*)d_in[14];
  const int* src_fol  = (const int*)d_in[15];
  const int* dst_fol  = (const int*)d_in[16];
  const int* tgt      = (const int*)d_in[17];
  float* outp = (float*)d_out;

  char* wp = (char*)d_ws;
  size_t ob = 0;
  auto take = [&](size_t bytes) -> void* {
    void* p = wp + ob;
    ob += (bytes + 255) & ~(size_t)255;
    return p;
  };
  int*            cnt     = (int*)           take((size_t)NNODE * 4);
  int*            offs    = (int*)           take((size_t)NNODE * 4);
  int*            cntBB   = (int*)           take((size_t)NRUN * 4);
  int*            sscan   = (int*)           take((size_t)(NRUN + 1) * 4);
  int*            partial = (int*)           take((size_t)NSCANB * 4);
  int*            pbase   = (int*)           take((size_t)NSCANB * 4);
  int*            esrc    = (int*)           take((size_t)3 * NEDGE * 4);
  float*          Wrc     = (float*)         take((size_t)2 * NH * NH * 4);
  float*          bc      = (float*)         take((size_t)2 * NH * 4);
  unsigned short* meanL1b = (unsigned short*)take((size_t)NNODE * NH * 2);
  unsigned short* ub      = (unsigned short*)take((size_t)N_USERS * NH * 2);
  unsigned short* ib      = (unsigned short*)take((size_t)N_ITEMS * NH * 2);
  unsigned short* xu1b    = (unsigned short*)take((size_t)N_USERS * NH * 2);
  unsigned short* xi1b    = (unsigned short*)take((size_t)N_ITEMS * NH * 2);
  unsigned short* Wlb     = (unsigned short*)take((size_t)6 * NH * NH * 2);  // all Wl bf16
  unsigned short* Wrb00   = (unsigned short*)take((size_t)NH * NH * 2);      // Wr[0,0] bf16
  unsigned short* Wrcb    = (unsigned short*)take((size_t)NH * NH * 2);      // Wrc[0] bf16
  float*          mrev2   = (float*)         take((size_t)NTGT * NH * 4);
  float*          mfol2   = (float*)         take((size_t)NTGT * NH * 4);
  float*          xsel2   = (float*)         take((size_t)NTGT * NH * 4);
  float*          h2      = (float*)         take((size_t)NTGT * NH * 4);
  // binned edge buffer (9.6 MB) aliases meanL1b (64 MB): consumed by k_csr
  // before k_agg1 writes meanL1b.
  int*            binned  = (int*)meanL1b;

  k_combine<<<(2 * NH * NH + 2 * NH + 255) / 256, 256, 0, stream>>>(Wr, bl, Wrc, bc);
  k_tobf16<<<N_USERS * NH / 2048, 256, 0, stream>>>(emb_user, (unsigned*)ub);
  k_tobf16<<<N_ITEMS * NH / 2048, 256, 0, stream>>>(emb_item, (unsigned*)ib);
  k_tobf16<<<6 * NH * NH / 2048, 256, 0, stream>>>(Wl, (unsigned*)Wlb);
  k_tobf16<<<NH * NH / 2048, 256, 0, stream>>>(Wr, (unsigned*)Wrb00);
  k_tobf16<<<NH * NH / 2048, 256, 0, stream>>>(Wrc, (unsigned*)Wrcb);
  k_pcount<<<NBLK, 256, 0, stream>>>(dst_buys, dst_rev, dst_fol, cntBB);
  k_scanA<<<NSCANB, 256, 0, stream>>>(cntBB, partial);
  k_scanB<<<1, 256, 0, stream>>>(partial, pbase);
  k_scanC<<<NSCANB, 256, 0, stream>>>(cntBB, pbase, sscan);
  k_pfill<<<NBLK, 256, 0, stream>>>(
      src_buys, dst_buys, src_rev, dst_rev, src_fol, dst_fol, sscan, binned);
  k_csr<<<NBUCK, 256, 0, stream>>>(binned, sscan, cnt, offs, esrc);
  k_agg1<<<(NNODE + 7) / 8, 256, 0, stream>>>(offs, cnt, esrc,
      (const unsigned*)ub, (const unsigned*)ib, (unsigned*)meanL1b);

  // layer-1 item: relu(LN(mean_buys@Wl00^T + xi0@Wr00^T + bl00)) -> bf16 (MFMA)
  k_mfma_ln<<<(N_ITEMS + 127) / 128, 256, 0, stream>>>(
      meanL1b, Wlb + 0 * NH * NH,
      ib, Wrb00,
      nullptr, nullptr,
      bl + 0 * NH, ln_g + 1 * NH, ln_b + 1 * NH, xi1b, N_ITEMS);

  // layer-1 user: relu(LN(mean_rev@Wl01^T + mean_fol@Wl02^T + xu0@Wrc0^T + bc0)) -> bf16 (MFMA)
  k_mfma_ln<<<(N_USERS + 127) / 128, 256, 0, stream>>>(
      meanL1b + (size_t)BASE_REV * NH, Wlb + 1 * NH * NH,
      meanL1b + (size_t)BASE_FOL * NH, Wlb + 2 * NH * NH,
      ub, Wrcb,
      bc, ln_g + 0 * NH, ln_b + 0 * NH, xu1b, N_USERS);

  // layer-2 aggregation at targets only (item update is dead code)
  k_agg_tgt<<<(2 * NTGT + 7) / 8, 256, 0, stream>>>(
      tgt, offs, cnt, esrc, (const unsigned*)xu1b, (const unsigned*)xi1b,
      mrev2, mfol2, xsel2);

  // layer-2 user at targets (fp32 VALU, protects the output head)
  k_gemm_ln<<<(NTGT + 63) / 64, 256, 0, stream>>>(
      mrev2, Wl + (1 * 3 + 1) * NH * NH,
      mfol2, Wl + (1 * 3 + 2) * NH * NH,
      xsel2, Wrc + NH * NH,
      bc + NH, ln_g + 2 * NH, ln_b + 2 * NH, h2, NTGT);

  // final MLP
  k_mlp<<<NTGT / 32, 256, 0, stream>>>(h2, W1, b1, W2, b2, outp);
}

// Round 7
// 480.008 us; speedup vs baseline: 1.3251x; 1.0304x over previous
//
#include <hip/hip_runtime.h>

#define N_USERS 100000
#define N_ITEMS 50000
#define NEDGE   800000
#define NH      128
#define NHNH    16384
#define NTGT    8192
#define NNODE   250000      // 50K item slots (buys) + 100K user (rev) + 100K user (fol)
#define BASE_REV 50000
#define BASE_FOL 150000
#define NBUCK   588         // 196 buys (256 nodes) + 196 rev (512) + 196 fol (512)
#define NBLK    384         // binning blocks
#define NPB     6250        // edges per binning block: 384*6250 = 2400000 exactly
#define NRUN    (NBUCK * NBLK)        // 225792 per-(bucket,block) runs
#define NSCANB  441                   // 225792 / 512 exactly

typedef __attribute__((ext_vector_type(8))) short short8;
typedef __attribute__((ext_vector_type(4))) float f32x4;
typedef __attribute__((ext_vector_type(2))) float f32x2;

// ---------------------------------------------------------------- bf16 helpers (RNE, manual)
__device__ __forceinline__ unsigned rne_hi(float f) {
  unsigned u = __float_as_uint(f);
  u += 0x7FFFu + ((u >> 16) & 1u);
  return u & 0xFFFF0000u;
}
__device__ __forceinline__ unsigned pack2(float f0, float f1) {
  return (rne_hi(f0) >> 16) | rne_hi(f1);   // low ushort = f0, high = f1
}
__device__ __forceinline__ float blo(unsigned u) { return __uint_as_float(u << 16); }
__device__ __forceinline__ float bhi(unsigned u) { return __uint_as_float(u & 0xFFFF0000u); }

__device__ __forceinline__ int bucket_of(int n) {
  return (n < BASE_REV) ? (n >> 8)
       : (n < BASE_FOL) ? 196 + ((n - BASE_REV) >> 9)
                        : 392 + ((n - BASE_FOL) >> 9);
}

// ---------------------------------------------------------------- fused prep: bf16 conversions + Wr/bl combines
// block ranges: [0,6250) ub | [6250,9375) ib | [9375,9423) Wlb |
//               [9423,9431) Wrb00 | [9431,9439) Wrc0+Wrcb | [9439,9447) Wrc1 | 9447 bc
__global__ __launch_bounds__(256) void k_prep(
    const float* __restrict__ eu, const float* __restrict__ ei,
    const float* __restrict__ Wl, const float* __restrict__ Wr,
    const float* __restrict__ bl,
    unsigned* __restrict__ ub, unsigned* __restrict__ ib,
    unsigned* __restrict__ Wlb, unsigned* __restrict__ Wrb00,
    float* __restrict__ Wrc, unsigned* __restrict__ Wrcb, float* __restrict__ bc)
{
  int b = blockIdx.x, t = threadIdx.x;
  if (b < 9431) {
    const float* src; unsigned* dst; int i;
    if (b < 6250)      { src = eu; dst = ub;    i = b * 256 + t; }
    else if (b < 9375) { src = ei; dst = ib;    i = (b - 6250) * 256 + t; }
    else if (b < 9423) { src = Wl; dst = Wlb;   i = (b - 9375) * 256 + t; }
    else               { src = Wr; dst = Wrb00; i = (b - 9423) * 256 + t; }
    const float4* xp = (const float4*)src;
    float4 a = xp[(size_t)i * 2];
    float4 c = xp[(size_t)i * 2 + 1];
    ((uint4*)dst)[i] = make_uint4(pack2(a.x, a.y), pack2(a.z, a.w),
                                  pack2(c.x, c.y), pack2(c.z, c.w));
  } else if (b < 9439) {
    int i = (b - 9431) * 256 + t;      // uint4 index into 16384-elem matrix
    const float4* w1 = (const float4*)(Wr + 1 * NHNH);
    const float4* w2 = (const float4*)(Wr + 2 * NHNH);
    float4 a1 = w1[(size_t)i * 2],     a2 = w2[(size_t)i * 2];
    float4 c1 = w1[(size_t)i * 2 + 1], c2 = w2[(size_t)i * 2 + 1];
    float4 a = make_float4(a1.x + a2.x, a1.y + a2.y, a1.z + a2.z, a1.w + a2.w);
    float4 c = make_float4(c1.x + c2.x, c1.y + c2.y, c1.z + c2.z, c1.w + c2.w);
    ((float4*)Wrc)[(size_t)i * 2]     = a;
    ((float4*)Wrc)[(size_t)i * 2 + 1] = c;
    ((uint4*)Wrcb)[i] = make_uint4(pack2(a.x, a.y), pack2(a.z, a.w),
                                   pack2(c.x, c.y), pack2(c.z, c.w));
  } else if (b < 9447) {
    int i = (b - 9439) * 256 + t;
    const float4* w1 = (const float4*)(Wr + 4 * NHNH);
    const float4* w2 = (const float4*)(Wr + 5 * NHNH);
    float4 a1 = w1[(size_t)i * 2],     a2 = w2[(size_t)i * 2];
    float4 c1 = w1[(size_t)i * 2 + 1], c2 = w2[(size_t)i * 2 + 1];
    ((float4*)(Wrc + NHNH))[(size_t)i * 2] =
        make_float4(a1.x + a2.x, a1.y + a2.y, a1.z + a2.z, a1.w + a2.w);
    ((float4*)(Wrc + NHNH))[(size_t)i * 2 + 1] =
        make_float4(c1.x + c2.x, c1.y + c2.y, c1.z + c2.z, c1.w + c2.w);
  } else {
    if (t < NH)       bc[t]      = bl[1 * NH + t] + bl[2 * NH + t];
    else if (t < 2*NH) { int r = t - NH; bc[NH + r] = bl[4 * NH + r] + bl[5 * NH + r]; }
  }
}

// ---------------------------------------------------------------- pass A: per-(bucket,block) histogram, LDS only
__global__ __launch_bounds__(256) void k_pcount(
    const int* __restrict__ db, const int* __restrict__ dr,
    const int* __restrict__ df, int* __restrict__ cntBB)
{
  __shared__ int h[NBUCK];
  int t = threadIdx.x, blk = blockIdx.x;
  for (int j = t; j < NBUCK; j += 256) h[j] = 0;
  __syncthreads();
  int ebase = blk * NPB;
  for (int i = t; i < NPB; i += 256) {
    int e = ebase + i, n;
    if (e < NEDGE)          n = db[e];
    else if (e < 2 * NEDGE) n = BASE_REV + dr[e - NEDGE];
    else                    n = BASE_FOL + df[e - 2 * NEDGE];
    atomicAdd(&h[bucket_of(n)], 1);
  }
  __syncthreads();
  for (int j = t; j < NBUCK; j += 256) cntBB[j * NBLK + blk] = h[j];
}

// ---------------------------------------------------------------- scan of 225792 counts (3 tiny kernels)
__global__ __launch_bounds__(256) void k_scanA(const int* __restrict__ cntBB,
                                               int* __restrict__ partial)
{
  int t = threadIdx.x;
  int base = blockIdx.x * 512;
  int s = cntBB[base + t] + cntBB[base + 256 + t];
  __shared__ int red[256];
  red[t] = s; __syncthreads();
  for (int d = 128; d > 0; d >>= 1) { if (t < d) red[t] += red[t + d]; __syncthreads(); }
  if (t == 0) partial[blockIdx.x] = red[0];
}

__global__ __launch_bounds__(256) void k_scanB(const int* __restrict__ partial,
                                               int* __restrict__ pbase)
{
  __shared__ int carry;
  __shared__ int wsum[4];
  int t = threadIdx.x, lane = t & 63, w = t >> 6;
  if (t == 0) carry = 0;
  __syncthreads();
  for (int base = 0; base < NSCANB; base += 256) {
    int orig = (base + t < NSCANB) ? partial[base + t] : 0;
    int v = orig;
    #pragma unroll
    for (int o = 1; o < 64; o <<= 1) { int u = __shfl_up(v, o); if (lane >= o) v += u; }
    if (lane == 63) wsum[w] = v;
    __syncthreads();
    int wb = 0;
    for (int i = 0; i < w; ++i) wb += wsum[i];
    int excl = carry + wb + v - orig;
    if (base + t < NSCANB) pbase[base + t] = excl;
    __syncthreads();
    if (t == 255) carry = excl + orig;
    __syncthreads();
  }
}

__global__ __launch_bounds__(256) void k_scanC(const int* __restrict__ cntBB,
                                               const int* __restrict__ pbase,
                                               int* __restrict__ sscan)
{
  int t = threadIdx.x, blk = blockIdx.x;
  int base = blk * 512;
  int a0 = cntBB[base + t * 2], a1 = cntBB[base + t * 2 + 1];
  int sum = a0 + a1;
  int lane = t & 63, w = t >> 6;
  int v = sum;
  #pragma unroll
  for (int o = 1; o < 64; o <<= 1) { int u = __shfl_up(v, o); if (lane >= o) v += u; }
  __shared__ int wsum[4];
  if (lane == 63) wsum[w] = v;
  __syncthreads();
  int wb = 0;
  for (int i = 0; i < w; ++i) wb += wsum[i];
  int excl = wb + v - sum;
  int P = pbase[blk];
  sscan[base + t * 2]     = P + excl;
  sscan[base + t * 2 + 1] = P + excl + a0;
  if (blk == NSCANB - 1 && t == 255)
    sscan[NRUN] = P + wsum[0] + wsum[1] + wsum[2] + wsum[3];   // == 3*NEDGE
}

// ---------------------------------------------------------------- pass B: scatter into pre-reserved runs (LDS cursors only)
__global__ __launch_bounds__(256) void k_pfill(
    const int* __restrict__ sb, const int* __restrict__ db,
    const int* __restrict__ sr, const int* __restrict__ dr,
    const int* __restrict__ sf, const int* __restrict__ df,
    const int* __restrict__ sscan, int* __restrict__ binned)
{
  __shared__ int cur[NBUCK];
  int t = threadIdx.x, blk = blockIdx.x;
  for (int j = t; j < NBUCK; j += 256) cur[j] = sscan[j * NBLK + blk];
  __syncthreads();
  int ebase = blk * NPB;
  for (int i = t; i < NPB; i += 256) {
    int e = ebase + i, n, s;
    if (e < NEDGE)          { n = db[e];                      s = sb[e]; }
    else if (e < 2 * NEDGE) { n = BASE_REV + dr[e - NEDGE];   s = sr[e - NEDGE]; }
    else                    { n = BASE_FOL + df[e - 2*NEDGE]; s = sf[e - 2*NEDGE]; }
    int b = bucket_of(n);
    int local = (n < BASE_REV) ? (n & 255)
              : (n < BASE_FOL) ? ((n - BASE_REV) & 511)
                               : ((n - BASE_FOL) & 511);
    int pos = atomicAdd(&cur[b], 1);
    binned[pos] = (local << 17) | s;
  }
}

// ---------------------------------------------------------------- pass C: per-bucket CSR build (1 block / bucket)
__global__ __launch_bounds__(256) void k_csr(
    const int* __restrict__ binned, const int* __restrict__ sscan,
    int* __restrict__ cnt, int* __restrict__ offs, int* __restrict__ esrc)
{
  int b = blockIdx.x;
  int n0, S;
  if (b < 196)      { n0 = b * 256;                    S = min(256, BASE_REV - n0); }
  else if (b < 392) { n0 = BASE_REV + (b - 196) * 512; S = min(512, BASE_FOL - n0); }
  else              { n0 = BASE_FOL + (b - 392) * 512; S = min(512, NNODE - n0); }
  int e0 = sscan[b * NBLK];
  int e1 = sscan[(b + 1) * NBLK];
  int t = threadIdx.x;
  __shared__ int h[512], fl[512];
  __shared__ int wsum[4];
  h[t] = 0; h[t + 256] = 0;
  __syncthreads();
  for (int e = e0 + t; e < e1; e += 256)
    atomicAdd(&h[binned[e] >> 17], 1);
  __syncthreads();
  int a0 = h[t * 2], a1 = h[t * 2 + 1];
  int v = a0 + a1;
  int lane = t & 63, w = t >> 6;
  #pragma unroll
  for (int o = 1; o < 64; o <<= 1) { int u = __shfl_up(v, o); if (lane >= o) v += u; }
  if (lane == 63) wsum[w] = v;
  __syncthreads();
  int wb = 0;
  for (int i = 0; i < w; ++i) wb += wsum[i];
  int excl = wb + v - (a0 + a1);
  fl[t * 2]     = e0 + excl;
  fl[t * 2 + 1] = e0 + excl + a0;
  if (t * 2 < S)     { cnt[n0 + t * 2]     = a0; offs[n0 + t * 2]     = e0 + excl + a0; }
  if (t * 2 + 1 < S) { cnt[n0 + t * 2 + 1] = a1; offs[n0 + t * 2 + 1] = e0 + excl + a0 + a1; }
  __syncthreads();
  for (int e = e0 + t; e < e1; e += 256) {
    int v2 = binned[e];
    int p = atomicAdd(&fl[v2 >> 17], 1);
    esrc[p] = v2 & 0x1FFFF;
  }
}

// ---------------------------------------------------------------- layer-1 mean aggregation
// Quarter-wave: 16 lanes x uint4 (16B) = full 256B bf16 row; 4 node-streams
// per wave, unroll-8 -> 32 outstanding gathers/wave. fp32 (pk) accumulate.
__global__ __launch_bounds__(256) void k_agg1(
    const int* __restrict__ offs, const int* __restrict__ cnt,
    const int* __restrict__ esrc,
    const uint4* __restrict__ ub4, const uint4* __restrict__ ib4,
    uint4* __restrict__ mean4)
{
  int n = blockIdx.x * 16 + (threadIdx.x >> 4);
  int sl = threadIdx.x & 15;
  const uint4* table = (n < BASE_REV) ? ub4 : (n < BASE_FOL) ? ib4 : ub4;
  int end = offs[n], c = cnt[n], st = end - c;
  f32x2 a0 = {0.f, 0.f}, a1 = {0.f, 0.f}, a2 = {0.f, 0.f}, a3 = {0.f, 0.f};
  int k = st;
  for (; k + 7 < end; k += 8) {
    int s0 = esrc[k],     s1 = esrc[k + 1], s2 = esrc[k + 2], s3 = esrc[k + 3];
    int s4 = esrc[k + 4], s5 = esrc[k + 5], s6 = esrc[k + 6], s7 = esrc[k + 7];
    uint4 v0 = table[(size_t)s0 * 16 + sl];
    uint4 v1 = table[(size_t)s1 * 16 + sl];
    uint4 v2 = table[(size_t)s2 * 16 + sl];
    uint4 v3 = table[(size_t)s3 * 16 + sl];
    uint4 v4 = table[(size_t)s4 * 16 + sl];
    uint4 v5 = table[(size_t)s5 * 16 + sl];
    uint4 v6 = table[(size_t)s6 * 16 + sl];
    uint4 v7 = table[(size_t)s7 * 16 + sl];
    a0 += (f32x2){blo(v0.x), bhi(v0.x)} + (f32x2){blo(v1.x), bhi(v1.x)}
        + (f32x2){blo(v2.x), bhi(v2.x)} + (f32x2){blo(v3.x), bhi(v3.x)}
        + (f32x2){blo(v4.x), bhi(v4.x)} + (f32x2){blo(v5.x), bhi(v5.x)}
        + (f32x2){blo(v6.x), bhi(v6.x)} + (f32x2){blo(v7.x), bhi(v7.x)};
    a1 += (f32x2){blo(v0.y), bhi(v0.y)} + (f32x2){blo(v1.y), bhi(v1.y)}
        + (f32x2){blo(v2.y), bhi(v2.y)} + (f32x2){blo(v3.y), bhi(v3.y)}
        + (f32x2){blo(v4.y), bhi(v4.y)} + (f32x2){blo(v5.y), bhi(v5.y)}
        + (f32x2){blo(v6.y), bhi(v6.y)} + (f32x2){blo(v7.y), bhi(v7.y)};
    a2 += (f32x2){blo(v0.z), bhi(v0.z)} + (f32x2){blo(v1.z), bhi(v1.z)}
        + (f32x2){blo(v2.z), bhi(v2.z)} + (f32x2){blo(v3.z), bhi(v3.z)}
        + (f32x2){blo(v4.z), bhi(v4.z)} + (f32x2){blo(v5.z), bhi(v5.z)}
        + (f32x2){blo(v6.z), bhi(v6.z)} + (f32x2){blo(v7.z), bhi(v7.z)};
    a3 += (f32x2){blo(v0.w), bhi(v0.w)} + (f32x2){blo(v1.w), bhi(v1.w)}
        + (f32x2){blo(v2.w), bhi(v2.w)} + (f32x2){blo(v3.w), bhi(v3.w)}
        + (f32x2){blo(v4.w), bhi(v4.w)} + (f32x2){blo(v5.w), bhi(v5.w)}
        + (f32x2){blo(v6.w), bhi(v6.w)} + (f32x2){blo(v7.w), bhi(v7.w)};
  }
  for (; k < end; ++k) {
    uint4 v = table[(size_t)esrc[k] * 16 + sl];
    a0 += (f32x2){blo(v.x), bhi(v.x)};
    a1 += (f32x2){blo(v.y), bhi(v.y)};
    a2 += (f32x2){blo(v.z), bhi(v.z)};
    a3 += (f32x2){blo(v.w), bhi(v.w)};
  }
  float inv = 1.0f / fmaxf((float)c, 1.0f);
  mean4[(size_t)n * 16 + sl] =
      make_uint4(pack2(a0.x * inv, a0.y * inv), pack2(a1.x * inv, a1.y * inv),
                 pack2(a2.x * inv, a2.y * inv), pack2(a3.x * inv, a3.y * inv));
}

// ---------------------------------------------------------------- layer-2 target aggregation (quarter-wave)
__global__ __launch_bounds__(256) void k_agg_tgt(
    const int* __restrict__ tgt, const int* __restrict__ offs,
    const int* __restrict__ cnt, const int* __restrict__ esrc,
    const uint4* __restrict__ xu1b4, const uint4* __restrict__ xi1b4,
    float* __restrict__ mrev, float* __restrict__ mfol, float* __restrict__ xsel)
{
  int hw = blockIdx.x * 16 + (threadIdx.x >> 4);
  int sl = threadIdx.x & 15;
  int tg = hw >> 1, which = hw & 1;
  int u = tgt[tg];
  int n = (which ? BASE_FOL : BASE_REV) + u;
  const uint4* table = which ? xu1b4 : xi1b4;
  int end = offs[n], c = cnt[n], st = end - c;
  f32x2 a0 = {0.f, 0.f}, a1 = {0.f, 0.f}, a2 = {0.f, 0.f}, a3 = {0.f, 0.f};
  int k = st;
  for (; k + 7 < end; k += 8) {
    int s0 = esrc[k],     s1 = esrc[k + 1], s2 = esrc[k + 2], s3 = esrc[k + 3];
    int s4 = esrc[k + 4], s5 = esrc[k + 5], s6 = esrc[k + 6], s7 = esrc[k + 7];
    uint4 v0 = table[(size_t)s0 * 16 + sl];
    uint4 v1 = table[(size_t)s1 * 16 + sl];
    uint4 v2 = table[(size_t)s2 * 16 + sl];
    uint4 v3 = table[(size_t)s3 * 16 + sl];
    uint4 v4 = table[(size_t)s4 * 16 + sl];
    uint4 v5 = table[(size_t)s5 * 16 + sl];
    uint4 v6 = table[(size_t)s6 * 16 + sl];
    uint4 v7 = table[(size_t)s7 * 16 + sl];
    a0 += (f32x2){blo(v0.x), bhi(v0.x)} + (f32x2){blo(v1.x), bhi(v1.x)}
        + (f32x2){blo(v2.x), bhi(v2.x)} + (f32x2){blo(v3.x), bhi(v3.x)}
        + (f32x2){blo(v4.x), bhi(v4.x)} + (f32x2){blo(v5.x), bhi(v5.x)}
        + (f32x2){blo(v6.x), bhi(v6.x)} + (f32x2){blo(v7.x), bhi(v7.x)};
    a1 += (f32x2){blo(v0.y), bhi(v0.y)} + (f32x2){blo(v1.y), bhi(v1.y)}
        + (f32x2){blo(v2.y), bhi(v2.y)} + (f32x2){blo(v3.y), bhi(v3.y)}
        + (f32x2){blo(v4.y), bhi(v4.y)} + (f32x2){blo(v5.y), bhi(v5.y)}
        + (f32x2){blo(v6.y), bhi(v6.y)} + (f32x2){blo(v7.y), bhi(v7.y)};
    a2 += (f32x2){blo(v0.z), bhi(v0.z)} + (f32x2){blo(v1.z), bhi(v1.z)}
        + (f32x2){blo(v2.z), bhi(v2.z)} + (f32x2){blo(v3.z), bhi(v3.z)}
        + (f32x2){blo(v4.z), bhi(v4.z)} + (f32x2){blo(v5.z), bhi(v5.z)}
        + (f32x2){blo(v6.z), bhi(v6.z)} + (f32x2){blo(v7.z), bhi(v7.z)};
    a3 += (f32x2){blo(v0.w), bhi(v0.w)} + (f32x2){blo(v1.w), bhi(v1.w)}
        + (f32x2){blo(v2.w), bhi(v2.w)} + (f32x2){blo(v3.w), bhi(v3.w)}
        + (f32x2){blo(v4.w), bhi(v4.w)} + (f32x2){blo(v5.w), bhi(v5.w)}
        + (f32x2){blo(v6.w), bhi(v6.w)} + (f32x2){blo(v7.w), bhi(v7.w)};
  }
  for (; k < end; ++k) {
    uint4 v = table[(size_t)esrc[k] * 16 + sl];
    a0 += (f32x2){blo(v.x), bhi(v.x)};
    a1 += (f32x2){blo(v.y), bhi(v.y)};
    a2 += (f32x2){blo(v.z), bhi(v.z)};
    a3 += (f32x2){blo(v.w), bhi(v.w)};
  }
  float inv = 1.0f / fmaxf((float)c, 1.0f);
  float4 o0 = make_float4(a0.x * inv, a0.y * inv, a1.x * inv, a1.y * inv);
  float4 o1 = make_float4(a2.x * inv, a2.y * inv, a3.x * inv, a3.y * inv);
  float* outp = which ? mfol : mrev;
  ((float4*)outp)[(size_t)tg * 32 + sl * 2]     = o0;
  ((float4*)outp)[(size_t)tg * 32 + sl * 2 + 1] = o1;
  if (!which) {
    uint4 xv = xu1b4[(size_t)u * 16 + sl];
    ((float4*)xsel)[(size_t)tg * 32 + sl * 2] =
        make_float4(blo(xv.x), bhi(xv.x), blo(xv.y), bhi(xv.y));
    ((float4*)xsel)[(size_t)tg * 32 + sl * 2 + 1] =
        make_float4(blo(xv.z), bhi(xv.z), blo(xv.w), bhi(xv.w));
  }
}

// ---------------------------------------------------------------- MFMA layer-1 GEMM + bias + LN + ReLU (bf16 in, bf16 out)
__global__ __launch_bounds__(256) void k_mfma_ln(
    const unsigned short* __restrict__ A0, const unsigned short* __restrict__ W0,
    const unsigned short* __restrict__ A1, const unsigned short* __restrict__ W1,
    const unsigned short* __restrict__ A2, const unsigned short* __restrict__ W2,
    const float* __restrict__ bias, const float* __restrict__ lng,
    const float* __restrict__ lnb, unsigned short* __restrict__ out, int M)
{
  __shared__ unsigned short ytile[4][32][132];
  const int t = threadIdx.x;
  const int wv = t >> 6, lane = t & 63;
  const int quad = lane >> 4, c0 = lane & 15;
  const int m0 = blockIdx.x * 128 + wv * 32;
  const int ko = quad * 8;

  f32x4 acc[2][8];
  #pragma unroll
  for (int i = 0; i < 2; ++i)
    #pragma unroll
    for (int j = 0; j < 8; ++j) acc[i][j] = (f32x4){0.f, 0.f, 0.f, 0.f};

  int gr0 = m0 + c0;      if (gr0 > M - 1) gr0 = M - 1;
  int gr1 = m0 + 16 + c0; if (gr1 > M - 1) gr1 = M - 1;

  #pragma unroll
  for (int term = 0; term < 3; ++term) {
    const unsigned short* A = (term == 0) ? A0 : (term == 1) ? A1 : A2;
    const unsigned short* W = (term == 0) ? W0 : (term == 1) ? W1 : W2;
    if (!A) continue;
    #pragma unroll
    for (int kc = 0; kc < NH; kc += 32) {
      short8 b[8];
      #pragma unroll
      for (int j = 0; j < 8; ++j)
        b[j] = *(const short8*)(W + (size_t)(16 * j + c0) * NH + kc + ko);
      short8 a0 = *(const short8*)(A + (size_t)gr0 * NH + kc + ko);
      short8 a1 = *(const short8*)(A + (size_t)gr1 * NH + kc + ko);
      #pragma unroll
      for (int j = 0; j < 8; ++j) {
        acc[0][j] = __builtin_amdgcn_mfma_f32_16x16x32_bf16(a0, b[j], acc[0][j], 0, 0, 0);
        acc[1][j] = __builtin_amdgcn_mfma_f32_16x16x32_bf16(a1, b[j], acc[1][j], 0, 0, 0);
      }
    }
  }

  float bb[8], gg[8], ll[8];
  #pragma unroll
  for (int j = 0; j < 8; ++j) {
    bb[j] = bias[16 * j + c0]; gg[j] = lng[16 * j + c0]; ll[j] = lnb[16 * j + c0];
  }

  #pragma unroll
  for (int i = 0; i < 2; ++i) {
    #pragma unroll
    for (int r = 0; r < 4; ++r) {
      float v[8]; float s = 0.f, ss = 0.f;
      #pragma unroll
      for (int j = 0; j < 8; ++j) {
        float x = acc[i][j][r] + bb[j];
        v[j] = x; s += x; ss += x * x;
      }
      #pragma unroll
      for (int o = 1; o < 16; o <<= 1) { s += __shfl_xor(s, o); ss += __shfl_xor(ss, o); }
      float mu = s * (1.0f / 128.0f);
      float var = ss * (1.0f / 128.0f) - mu * mu;
      float rinv = rsqrtf(var + 1e-5f);
      int rl = 16 * i + quad * 4 + r;
      #pragma unroll
      for (int j = 0; j < 8; ++j) {
        float y = fmaxf((v[j] - mu) * rinv * gg[j] + ll[j], 0.f);
        ytile[wv][rl][16 * j + c0] = (unsigned short)(rne_hi(y) >> 16);
      }
    }
  }
  __syncthreads();
  #pragma unroll
  for (int it = 0; it < 16; ++it) {
    int idx = it * 256 + t;
    int row = idx >> 5, c4 = (idx & 31) * 4;
    int gr = blockIdx.x * 128 + row;
    if (gr < M)
      *(uint2*)(out + (size_t)gr * NH + c4) = *(const uint2*)&ytile[row >> 5][row & 31][c4];
  }
}

// ---------------------------------------------------------------- fp32 GEMM + bias + LN + ReLU (target layer only)
__global__ __launch_bounds__(256) void k_gemm_ln(
    const float* __restrict__ A0, const float* __restrict__ W0,
    const float* __restrict__ A1, const float* __restrict__ W1,
    const float* __restrict__ A2, const float* __restrict__ W2,
    const float* __restrict__ bias, const float* __restrict__ lng,
    const float* __restrict__ lnb, float* __restrict__ out, int M)
{
  const int t = threadIdx.x;
  const int tx = t & 31, ty = t >> 5;
  const int rowbase = blockIdx.x * 64;
  __shared__ float As[32][68];
  __shared__ float Ws[32 * 132];

  float acc[8][4];
  #pragma unroll
  for (int i = 0; i < 8; ++i)
    #pragma unroll
    for (int j = 0; j < 4; ++j) acc[i][j] = 0.f;

  const int arow = t >> 2;
  const int ak8  = (t & 3) * 8;

  #pragma unroll
  for (int term = 0; term < 3; ++term) {
    const float* A = (term == 0) ? A0 : (term == 1) ? A1 : A2;
    const float* W = (term == 0) ? W0 : (term == 1) ? W1 : W2;
    if (A == nullptr) continue;
    for (int kc = 0; kc < NH; kc += 32) {
      {
        int gr = rowbase + arow; if (gr > M - 1) gr = M - 1;
        const float* ap = &A[(size_t)gr * NH + kc + ak8];
        float4 v0 = *(const float4*)(ap);
        float4 v1 = *(const float4*)(ap + 4);
        As[ak8 + 0][arow] = v0.x; As[ak8 + 1][arow] = v0.y;
        As[ak8 + 2][arow] = v0.z; As[ak8 + 3][arow] = v0.w;
        As[ak8 + 4][arow] = v1.x; As[ak8 + 5][arow] = v1.y;
        As[ak8 + 6][arow] = v1.z; As[ak8 + 7][arow] = v1.w;
      }
      #pragma unroll
      for (int i = 0; i < 4; ++i) {
        int linear = t * 4 + i * 1024;
        int j = linear >> 5, k4 = linear & 31;
        float4 v = *(const float4*)&W[j * NH + kc + k4];
        Ws[(k4 + 0) * 132 + j] = v.x; Ws[(k4 + 1) * 132 + j] = v.y;
        Ws[(k4 + 2) * 132 + j] = v.z; Ws[(k4 + 3) * 132 + j] = v.w;
      }
      __syncthreads();
      #pragma unroll
      for (int kk = 0; kk < 32; ++kk) {
        float4 alo = *(const float4*)&As[kk][ty * 8];
        float4 ahi = *(const float4*)&As[kk][ty * 8 + 4];
        float4 w4  = *(const float4*)&Ws[kk * 132 + tx * 4];
        float ar[8] = {alo.x, alo.y, alo.z, alo.w, ahi.x, ahi.y, ahi.z, ahi.w};
        float wr[4] = {w4.x, w4.y, w4.z, w4.w};
        #pragma unroll
        for (int i = 0; i < 8; ++i)
          #pragma unroll
          for (int j = 0; j < 4; ++j)
            acc[i][j] = fmaf(ar[i], wr[j], acc[i][j]);
      }
      __syncthreads();
    }
  }

  float4 b4 = *(const float4*)&bias[tx * 4];
  float4 g4 = *(const float4*)&lng[tx * 4];
  float4 l4 = *(const float4*)&lnb[tx * 4];
  float bb[4] = {b4.x, b4.y, b4.z, b4.w};
  float gg[4] = {g4.x, g4.y, g4.z, g4.w};
  float ll[4] = {l4.x, l4.y, l4.z, l4.w};

  #pragma unroll
  for (int i = 0; i < 8; ++i) {
    float s = 0.f, ss = 0.f;
    #pragma unroll
    for (int j = 0; j < 4; ++j) {
      float v = acc[i][j] + bb[j];
      acc[i][j] = v;
      s += v; ss += v * v;
    }
    #pragma unroll
    for (int o = 1; o < 32; o <<= 1) { s += __shfl_xor(s, o); ss += __shfl_xor(ss, o); }
    float mu = s * (1.0f / 128.0f);
    float var = ss * (1.0f / 128.0f) - mu * mu;
    float rinv = rsqrtf(var + 1e-5f);
    int gr = rowbase + ty * 8 + i;
    if (gr < M) {
      float4 y;
      y.x = fmaxf((acc[i][0] - mu) * rinv * gg[0] + ll[0], 0.f);
      y.y = fmaxf((acc[i][1] - mu) * rinv * gg[1] + ll[1], 0.f);
      y.z = fmaxf((acc[i][2] - mu) * rinv * gg[2] + ll[2], 0.f);
      y.w = fmaxf((acc[i][3] - mu) * rinv * gg[3] + ll[3], 0.f);
      *(float4*)&out[(size_t)gr * NH + tx * 4] = y;
    }
  }
}

// ---------------------------------------------------------------- final MLP: relu(h@W1.T+b1)@W2.T+b2
__global__ __launch_bounds__(256) void k_mlp(
    const float* __restrict__ h2, const float* __restrict__ W1,
    const float* __restrict__ b1, const float* __restrict__ W2,
    const float* __restrict__ b2, float* __restrict__ out)
{
  __shared__ float W1s[64 * 129];
  __shared__ float b1s[64];
  __shared__ float W2s[64];
  __shared__ float sx[4][128];
  int t = threadIdx.x;
  #pragma unroll
  for (int i = 0; i < 32; ++i) {
    int idx = t + 256 * i;
    int j = idx >> 7, k = idx & 127;
    W1s[j * 129 + k] = W1[idx];
  }
  if (t < 64) { b1s[t] = b1[t]; W2s[t] = W2[t]; }
  __syncthreads();
  int w = t >> 6, lane = t & 63;
  float b2v = b2[0];
  for (int it = 0; it < 8; ++it) {
    int r = blockIdx.x * 32 + it * 4 + w;
    sx[w][lane]      = h2[(size_t)r * NH + lane];
    sx[w][lane + 64] = h2[(size_t)r * NH + lane + 64];
    __syncthreads();
    float h = b1s[lane];
    #pragma unroll
    for (int k = 0; k < 128; ++k) h = fmaf(sx[w][k], W1s[lane * 129 + k], h);
    h = fmaxf(h, 0.f);
    float p = h * W2s[lane];
    #pragma unroll
    for (int o = 32; o > 0; o >>= 1) p += __shfl_down(p, o);
    if (lane == 0) out[r] = p + b2v;
    __syncthreads();
  }
}

// ---------------------------------------------------------------- launch
extern "C" void kernel_launch(void* const* d_in, const int* in_sizes, int n_in,
                              void* d_out, int out_size, void* d_ws, size_t ws_size,
                              hipStream_t stream)
{
  const float* emb_user = (const float*)d_in[0];
  const float* emb_item = (const float*)d_in[1];
  const float* Wl   = (const float*)d_in[2];   // [2,3,128,128]
  const float* bl   = (const float*)d_in[3];   // [2,3,128]
  const float* Wr   = (const float*)d_in[4];   // [2,3,128,128]
  const float* ln_g = (const float*)d_in[5];   // [2,2,128]
  const float* ln_b = (const float*)d_in[6];   // [2,2,128]
  const float* W1   = (const float*)d_in[7];   // [64,128]
  const float* b1   = (const float*)d_in[8];   // [64]
  const float* W2   = (const float*)d_in[9];   // [1,64]
  const float* b2   = (const float*)d_in[10];  // [1]
  const int* src_buys = (const int*)d_in[11];
  const int* dst_buys = (const int*)d_in[12];
  const int* src_rev  = (const int*)d_in[13];
  const int* dst_rev  = (const int*)d_in[14];
  const int* src_fol  = (const int*)d_in[15];
  const int* dst_fol  = (const int*)d_in[16];
  const int* tgt      = (const int*)d_in[17];
  float* outp = (float*)d_out;

  char* wp = (char*)d_ws;
  size_t ob = 0;
  auto take = [&](size_t bytes) -> void* {
    void* p = wp + ob;
    ob += (bytes + 255) & ~(size_t)255;
    return p;
  };
  int*            cnt     = (int*)           take((size_t)NNODE * 4);
  int*            offs    = (int*)           take((size_t)NNODE * 4);
  int*            cntBB   = (int*)           take((size_t)NRUN * 4);
  int*            sscan   = (int*)           take((size_t)(NRUN + 1) * 4);
  int*            partial = (int*)           take((size_t)NSCANB * 4);
  int*            pbase   = (int*)           take((size_t)NSCANB * 4);
  int*            esrc    = (int*)           take((size_t)3 * NEDGE * 4);
  float*          Wrc     = (float*)         take((size_t)2 * NHNH * 4);
  float*          bc      = (float*)         take((size_t)2 * NH * 4);
  unsigned short* meanL1b = (unsigned short*)take((size_t)NNODE * NH * 2);
  unsigned short* ub      = (unsigned short*)take((size_t)N_USERS * NH * 2);
  unsigned short* ib      = (unsigned short*)take((size_t)N_ITEMS * NH * 2);
  unsigned short* xu1b    = (unsigned short*)take((size_t)N_USERS * NH * 2);
  unsigned short* xi1b    = (unsigned short*)take((size_t)N_ITEMS * NH * 2);
  unsigned short* Wlb     = (unsigned short*)take((size_t)6 * NHNH * 2);
  unsigned short* Wrb00   = (unsigned short*)take((size_t)NHNH * 2);
  unsigned short* Wrcb    = (unsigned short*)take((size_t)NHNH * 2);
  float*          mrev2   = (float*)         take((size_t)NTGT * NH * 4);
  float*          mfol2   = (float*)         take((size_t)NTGT * NH * 4);
  float*          xsel2   = (float*)         take((size_t)NTGT * NH * 4);
  float*          h2      = (float*)         take((size_t)NTGT * NH * 4);
  // binned edge buffer (9.6 MB) aliases meanL1b (64 MB): consumed by k_csr
  // before k_agg1 writes meanL1b.
  int*            binned  = (int*)meanL1b;

  k_prep<<<9448, 256, 0, stream>>>(emb_user, emb_item, Wl, Wr, bl,
      (unsigned*)ub, (unsigned*)ib, (unsigned*)Wlb, (unsigned*)Wrb00,
      Wrc, (unsigned*)Wrcb, bc);
  k_pcount<<<NBLK, 256, 0, stream>>>(dst_buys, dst_rev, dst_fol, cntBB);
  k_scanA<<<NSCANB, 256, 0, stream>>>(cntBB, partial);
  k_scanB<<<1, 256, 0, stream>>>(partial, pbase);
  k_scanC<<<NSCANB, 256, 0, stream>>>(cntBB, pbase, sscan);
  k_pfill<<<NBLK, 256, 0, stream>>>(
      src_buys, dst_buys, src_rev, dst_rev, src_fol, dst_fol, sscan, binned);
  k_csr<<<NBUCK, 256, 0, stream>>>(binned, sscan, cnt, offs, esrc);
  k_agg1<<<NNODE / 16, 256, 0, stream>>>(offs, cnt, esrc,
      (const uint4*)ub, (const uint4*)ib, (uint4*)meanL1b);

  // layer-1 item: relu(LN(mean_buys@Wl00^T + xi0@Wr00^T + bl00)) -> bf16 (MFMA)
  k_mfma_ln<<<(N_ITEMS + 127) / 128, 256, 0, stream>>>(
      meanL1b, Wlb + 0 * NHNH,
      ib, Wrb00,
      nullptr, nullptr,
      bl + 0 * NH, ln_g + 1 * NH, ln_b + 1 * NH, xi1b, N_ITEMS);

  // layer-1 user: relu(LN(mean_rev@Wl01^T + mean_fol@Wl02^T + xu0@Wrc0^T + bc0)) -> bf16 (MFMA)
  k_mfma_ln<<<(N_USERS + 127) / 128, 256, 0, stream>>>(
      meanL1b + (size_t)BASE_REV * NH, Wlb + 1 * NHNH,
      meanL1b + (size_t)BASE_FOL * NH, Wlb + 2 * NHNH,
      ub, Wrcb,
      bc, ln_g + 0 * NH, ln_b + 0 * NH, xu1b, N_USERS);

  // layer-2 aggregation at targets only (item update is dead code)
  k_agg_tgt<<<2 * NTGT / 16, 256, 0, stream>>>(
      tgt, offs, cnt, esrc, (const uint4*)xu1b, (const uint4*)xi1b,
      mrev2, mfol2, xsel2);

  // layer-2 user at targets (fp32 VALU, protects the output head)
  k_gemm_ln<<<(NTGT + 63) / 64, 256, 0, stream>>>(
      mrev2, Wl + (1 * 3 + 1) * NHNH,
      mfol2, Wl + (1 * 3 + 2) * NHNH,
      xsel2, Wrc + NHNH,
      bc + NH, ln_g + 2 * NH, ln_b + 2 * NH, h2, NTGT);

  // final MLP
  k_mlp<<<NTGT / 32, 256, 0, stream>>>(h2, W1, b1, W2, b2, outp);
}